// Round 17
// baseline (481.493 us; speedup 1.0000x reference)
//
#include <hip/hip_runtime.h>
#include <hip/hip_bf16.h>

typedef unsigned short u16t;
typedef unsigned int   u32t;
typedef unsigned long long u64t;

#define NNODE 100000
#define DIN   256
#define HIDN  128
#define DOUTN 64
#define NNZE  1600000
#define EDIR  500000
#define EBI   1000000
#define G64   1563           // ceil(NNODE/64)
#define NBIN  782            // ceil(NNODE/128), bin = key>>7
#define CH3   4096           // edges per partition block
#define K3G   391            // ceil(NNZE/CH3)
#define K3B   245            // ceil(EBI/CH3)
#define K3E   123            // ceil(EDIR/CH3)
#define KPART (K3G+K3B+K3E)  // 759 partition blocks
#define CAPG  2432           // gcn entries per bin cap
#define CAPB  1536           // bi entries per bin cap
#define CAPE  896            // dir-edge entries per bin cap (mean 640, sd 25 -> 10 sigma)

typedef __attribute__((ext_vector_type(8))) short bf16x8;
typedef __attribute__((ext_vector_type(4))) float f32x4;
typedef __attribute__((ext_vector_type(4))) float f4v;

__device__ __forceinline__ u32t pk2bf(float a, float b){
  __hip_bfloat162 h = __float22bfloat162_rn(make_float2(a, b));
  union { __hip_bfloat162 h2; u32t u; } c; c.h2 = h; return c.u;
}
__device__ __forceinline__ u16t s2bf(float a){
  __hip_bfloat16 h = __float2bfloat16(a);
  union { __hip_bfloat16 h1; u16t u; } c; c.h1 = h; return c.u;
}
__device__ __forceinline__ float2 up2(u32t w){
  return make_float2(__uint_as_float(w<<16), __uint_as_float(w&0xFFFF0000u));
}

// ---------------- union: coarse histogram (3 streams) + weight prep ----------------
__global__ __launch_bounds__(256) void histprep_kernel(const int* __restrict__ gi,
                                                       const int* __restrict__ be,
                                                       const int* __restrict__ ed,
                                                       u32t* __restrict__ gcnt_c,
                                                       u32t* __restrict__ bcnt_c,
                                                       u32t* __restrict__ ecnt_c,
                                                       const float* __restrict__ Wg,
                                                       const float* __restrict__ Wm,
                                                       const float* __restrict__ Wsg,
                                                       u16t* __restrict__ Wg_pre,
                                                       u16t* __restrict__ Wc_pre){
  __shared__ u32t h[1024];
  int blk = blockIdx.x, t = threadIdx.x;
  if(blk >= KPART){
    int idx = (blk-KPART)*256 + t;              // 0..65535
    int e = idx & 7, l = (idx>>3) & 63, f = (idx>>9) & 63, sel = idx>>15;
    int k_in = ((e>>2)<<4) + ((l>>4)<<2) + (e&3);
    if(sel == 0){
      int ks = f>>3, nf = f&7;
      int k = ks*32 + k_in, n = nf*16 + (l&15);
      Wg_pre[idx] = s2bf(Wg[(size_t)k*HIDN + n]);
    } else {
      int ks = f>>4, nf = f&15;
      int k = ks*32 + k_in, c = nf*16 + (l&15);
      int half = c>>7, ci = c&127;
      const float* src = (ci&1) ? Wsg : Wm;
      Wc_pre[idx - 32768] = s2bf(src[(size_t)(half*128 + k)*DOUTN + (ci>>1)]);
    }
    return;
  }
  const int* keys; u32t* outc; int E, e0;
  if(blk < K3G)          { keys=gi; outc=gcnt_c; E=NNZE; e0=blk*CH3; }
  else if(blk < K3G+K3B) { keys=be; outc=bcnt_c; E=EBI;  e0=(blk-K3G)*CH3; }
  else                   { keys=ed; outc=ecnt_c; E=EDIR; e0=(blk-K3G-K3B)*CH3; }
  for(int i=t;i<1024;i+=256) h[i]=0;
  __syncthreads();
  for(int i=t;i<CH3;i+=256){
    int e=e0+i;
    if(e<E) atomicAdd(&h[(u32t)keys[e]>>7], 1u);
  }
  __syncthreads();
  for(int b=t;b<1024;b+=256){
    u32t c=h[b];
    if(c) atomicAdd(&outc[b], c);
  }
}

// ---------------- scan coarse counts -> offsets + cursors (3 blocks) ----------------
__global__ __launch_bounds__(256) void scan_coarse_kernel(u32t* __restrict__ gcnt_c,
                                                          u32t* __restrict__ gcoff,
                                                          u32t* __restrict__ gcur_,
                                                          u32t* __restrict__ bcnt_c,
                                                          u32t* __restrict__ bcoff,
                                                          u32t* __restrict__ bcur_,
                                                          u32t* __restrict__ ecnt_c,
                                                          u32t* __restrict__ ecoff,
                                                          u32t* __restrict__ ecur_){
  __shared__ u32t part[256];
  u32t *cnt, *coff, *cur;
  if(blockIdx.x==0)      { cnt=gcnt_c; coff=gcoff; cur=gcur_; }
  else if(blockIdx.x==1) { cnt=bcnt_c; coff=bcoff; cur=bcur_; }
  else                   { cnt=ecnt_c; coff=ecoff; cur=ecur_; }
  int t = threadIdx.x;
  u32t ch[4], s=0;
  #pragma unroll
  for(int j=0;j<4;j++){ int idx=t*4+j; ch[j] = (idx<NBIN)? cnt[idx] : 0u; s+=ch[j]; }
  part[t]=s; __syncthreads();
  for(int off=1;off<256;off<<=1){
    u32t x=(t>=off)?part[t-off]:0u;
    __syncthreads();
    part[t]+=x;
    __syncthreads();
  }
  u32t run=(t==0)?0u:part[t-1];
  #pragma unroll
  for(int j=0;j<4;j++){
    int idx=t*4+j;
    if(idx<NBIN){ coff[idx]=run; cur[idx]=run; run+=ch[j]; }
  }
  if(t==255) coff[NBIN]=part[255];
}

// ---------------- union: GEMM1 (blocks [0,G64)) + partition (3 streams, after) ----------------
__global__ __launch_bounds__(256) void partgemm1_kernel(const float* __restrict__ X,
                                                        const u16t* __restrict__ Wg_pre,
                                                        u16t* __restrict__ xwb,
                                                        const int* __restrict__ gi,
                                                        const float* __restrict__ gv,
                                                        const int* __restrict__ be,
                                                        const float* __restrict__ bv,
                                                        const int* __restrict__ ed,
                                                        u32t* __restrict__ gcur_,
                                                        u64t* __restrict__ gbuck,
                                                        u32t* __restrict__ bcur_,
                                                        u64t* __restrict__ bbuck,
                                                        u32t* __restrict__ ecur_,
                                                        u64t* __restrict__ ebuck){
  __shared__ __align__(16) char smem[50176];
  const int t = threadIdx.x;
  if(blockIdx.x < G64){
    // ---------------- GEMM1 path ----------------
    u16t* Xs = (u16t*)smem;                     // 32 KB, 8B-granule XOR-swizzled
    const int l = t & 63, w = t >> 6;
    const int row0 = blockIdx.x * 64;
    for(int i=0;i<16;i++){
      int m = w*16 + i;
      int mg = min(row0 + m, NNODE-1);
      f4v f = __builtin_nontemporal_load((const f4v*)&X[(size_t)mg*DIN + l*4]);
      u32t* p = (u32t*)&Xs[m*256 + ((l ^ (m&15))<<2)];
      p[0] = pk2bf(f[0], f[1]);
      p[1] = pk2bf(f[2], f[3]);
    }
    __syncthreads();
    f32x4 acc[8];
    #pragma unroll
    for(int nf=0;nf<8;nf++) acc[nf] = (f32x4)(0.f);
    const int lm = l & 15, l4 = l >> 4;
    const int mrow = w*16 + lm;
    #pragma unroll 1
    for(int ks=0; ks<8; ks++){
      int kg = ks*8 + l4;
      union { uint2 u2[2]; bf16x8 v; } a;
      a.u2[0] = *(const uint2*)&Xs[mrow*256 + ((kg     ^ lm)<<2)];
      a.u2[1] = *(const uint2*)&Xs[mrow*256 + (((kg+4) ^ lm)<<2)];
      #pragma unroll
      for(int nf=0;nf<8;nf++){
        union { uint4 u4; bf16x8 v; } b;
        b.u4 = *(const uint4*)&Wg_pre[(size_t)((ks*8+nf)*64 + l)*8];
        acc[nf] = __builtin_amdgcn_mfma_f32_16x16x32_bf16(a.v, b.v, acc[nf], 0, 0, 0);
      }
    }
    #pragma unroll
    for(int r=0;r<4;r++){
      int gr = row0 + w*16 + l4*4 + r;
      if(gr < NNODE){
        #pragma unroll
        for(int nf=0;nf<8;nf++)
          xwb[(size_t)gr*HIDN + nf*16 + lm] = s2bf(acc[nf][r]);
      }
    }
    return;
  }
  // ---------------- partition path (3 streams) ----------------
  u32t* hist = (u32t*)smem;               // 1024 u32: counts -> cursor -> base
  u32t* scn  = (u32t*)(smem+4096);
  u32t* prt  = (u32t*)(smem+8192);
  u64t* ebuf = (u64t*)(smem+9216);        // 4096 u64
  u16t* bins = (u16t*)(smem+41984);       // 4096 u16
  int blk = blockIdx.x - G64;
  const int *keys, *pay; const float* val; u32t* cursor; u64t* buck; int E, e0; bool eStream=false;
  if(blk < K3G)          { keys=gi; pay=gi+NNZE; val=gv; cursor=gcur_; buck=gbuck; E=NNZE; e0=blk*CH3; }
  else if(blk < K3G+K3B) { keys=be; pay=be+EBI;  val=bv; cursor=bcur_; buck=bbuck; E=EBI;  e0=(blk-K3G)*CH3; }
  else                   { keys=ed; pay=ed+EDIR; val=0;  cursor=ecur_; buck=ebuck; E=EDIR; e0=(blk-K3G-K3B)*CH3; eStream=true; }
  for(int i=t;i<1024;i+=256) hist[i]=0;
  __syncthreads();
  for(int i=t;i<CH3;i+=256){
    int e=e0+i;
    if(e<E) atomicAdd(&hist[(u32t)keys[e]>>7], 1u);
  }
  __syncthreads();
  u32t ch[4], s=0;
  #pragma unroll
  for(int j=0;j<4;j++){ ch[j]=hist[t*4+j]; s+=ch[j]; }
  prt[t]=s; __syncthreads();
  for(int off=1;off<256;off<<=1){
    u32t x=(t>=off)?prt[t-off]:0u;
    __syncthreads();
    prt[t]+=x;
    __syncthreads();
  }
  u32t run=(t==0)?0u:prt[t-1];
  #pragma unroll
  for(int j=0;j<4;j++){ scn[t*4+j]=run; run+=ch[j]; }
  __syncthreads();
  for(int i=t;i<1024;i+=256) hist[i]=scn[i];   // hist becomes local cursor
  __syncthreads();
  for(int i=t;i<CH3;i+=256){
    int e=e0+i;
    if(e<E){
      int k = keys[e];
      u32t b = (u32t)k>>7;
      u32t p = atomicAdd(&hist[b],1u);
      u64t hi = eStream ? (u64t)(u32t)e : (u64t)__float_as_uint(val[e]);
      u64t ent = (u64t)((u32t)pay[e] | (((u32t)k&127u)<<20)) | (hi<<32);
      ebuf[p]=ent; bins[p]=(u16t)b;
    }
  }
  __syncthreads();
  for(int b=t;b<1024;b+=256){
    u32t c = hist[b]-scn[b];
    u32t bs = c ? atomicAdd(&cursor[b], c) : 0u;
    hist[b] = bs;
  }
  __syncthreads();
  int totalValid = prt[255];
  for(int i=t;i<totalValid;i+=256){
    u32t b = bins[i];
    buck[ (size_t)hist[b] + (u32t)i - scn[b] ] = ebuf[i];
  }
}

// ---------------- GCN gather: bin-per-block, in-LDS CSR + gather (8x MLP) ----------------
__global__ __launch_bounds__(256) void gcn_gather2_kernel(const u16t* __restrict__ xwb,
                                                          const u64t* __restrict__ gbuck,
                                                          const u32t* __restrict__ gcoff,
                                                          u32t* __restrict__ hiddenw){
  __shared__ u64t ebuf[CAPG];
  __shared__ u32t hist[128], offs[129], cur[128], sc[128];
  int bin = blockIdx.x, t = threadIdx.x;
  u32t base = gcoff[bin], cnt = gcoff[bin+1] - base;
  if(t<128) hist[t]=0;
  __syncthreads();
  for(u32t i=t;i<cnt;i+=256)
    atomicAdd(&hist[(u32t)(gbuck[base+i]>>20)&127u], 1u);
  __syncthreads();
  if(t<128) sc[t]=hist[t];
  __syncthreads();
  for(int off=1;off<128;off<<=1){
    u32t x=(t>=off&&t<128)?sc[t-off]:0u;
    __syncthreads();
    if(t<128) sc[t]+=x;
    __syncthreads();
  }
  if(t<128){ offs[t+1]=sc[t]; cur[t]=sc[t]-hist[t]; if(t==0) offs[0]=0u; }
  __syncthreads();
  for(u32t i=t;i<cnt;i+=256){
    u64t e = gbuck[base+i];
    u32t p = atomicAdd(&cur[(u32t)(e>>20)&127u], 1u);
    ebuf[p]=e;
  }
  __syncthreads();
  int w=t>>6, l=t&63;
  const u32t* xww=(const u32t*)xwb;
  for(int idx=w; idx<128; idx+=4){
    int n = bin*128 + idx;
    if(n >= NNODE) continue;
    u32t s0=offs[idx], cnt2=offs[idx+1]-s0;
    float acc0=0.f, acc1=0.f;
    u32t nbr=(cnt2+7)&~7u;
    for(u32t j=0;j<nbr;j+=8){
      float2 xs[8]; float vs[8];
      #pragma unroll
      for(int q=0;q<8;q++){
        u32t jj=j+q;
        u64t e=(jj<cnt2)? ebuf[s0+jj] : 0ULL;
        vs[q]=__uint_as_float((u32t)(e>>32));
        xs[q]=up2(xww[(size_t)(e&0x1FFFFu)*64 + l]);
      }
      #pragma unroll
      for(int q=0;q<8;q++){ acc0+=vs[q]*xs[q].x; acc1+=vs[q]*xs[q].y; }
    }
    hiddenw[(size_t)n*64 + l] = pk2bf(acc0, acc1);
  }
}

// ---------------- GEMM2 (MFMA): SRCw (in-place over hiddenw) + DSTw ----------------
__global__ __launch_bounds__(256) void gemm2_kernel(u32t* __restrict__ hiddenw,
                                                    const u16t* __restrict__ Wc_pre,
                                                    u16t* __restrict__ DSTw){
  __shared__ __align__(16) u16t Hs[64*128];   // 16 KB
  const int t = threadIdx.x, l = t & 63, w = t >> 6;
  const int row0 = blockIdx.x * 64;
  for(int i=0;i<16;i++){
    int m = w*16 + i;
    int mg = min(row0 + m, NNODE-1);
    u32t v = hiddenw[(size_t)mg*64 + l];
    *(u32t*)&Hs[m*128 + (((l>>1) ^ (m&15))<<2) + ((l&1)<<1)] = v;
  }
  __syncthreads();
  f32x4 acc[16];
  #pragma unroll
  for(int nf=0;nf<16;nf++) acc[nf] = (f32x4)(0.f);
  const int lm = l & 15, l4 = l >> 4;
  const int mrow = w*16 + lm;
  #pragma unroll 1
  for(int ks=0; ks<4; ks++){
    int kg = ks*8 + l4;
    union { uint2 u2[2]; bf16x8 v; } a;
    a.u2[0] = *(const uint2*)&Hs[mrow*128 + ((kg     ^ lm)<<2)];
    a.u2[1] = *(const uint2*)&Hs[mrow*128 + (((kg+4) ^ lm)<<2)];
    #pragma unroll
    for(int nf=0;nf<16;nf++){
      union { uint4 u4; bf16x8 v; } b;
      b.u4 = *(const uint4*)&Wc_pre[(size_t)((ks*16+nf)*64 + l)*8];
      acc[nf] = __builtin_amdgcn_mfma_f32_16x16x32_bf16(a.v, b.v, acc[nf], 0, 0, 0);
    }
  }
  u16t* SRCw = (u16t*)hiddenw;   // in-place: this block's rows were staged above
  #pragma unroll
  for(int r=0;r<4;r++){
    int gr = row0 + w*16 + l4*4 + r;
    if(gr < NNODE){
      #pragma unroll
      for(int nf=0;nf<8;nf++)
        SRCw[(size_t)gr*HIDN + nf*16 + lm] = s2bf(acc[nf][r]);
      #pragma unroll
      for(int nf=8;nf<16;nf++)
        DSTw[(size_t)gr*HIDN + (nf-8)*16 + lm] = s2bf(acc[nf][r]);
    }
  }
}

// ---------------- union kernel: bi bins [0,NBIN) + s-binned edge heads [NBIN,2*NBIN) ----------------
__global__ __launch_bounds__(256) void edgebi2_kernel(const u16t* __restrict__ SRCb,
                                                      const u16t* __restrict__ DSTb,
                                                      const float* __restrict__ nin,
                                                      const float* __restrict__ nout,
                                                      float* __restrict__ ein,
                                                      float* __restrict__ eout,
                                                      const u64t* __restrict__ bbuck,
                                                      const u32t* __restrict__ bcoff,
                                                      const u64t* __restrict__ ebuck,
                                                      const u32t* __restrict__ ecoff,
                                                      const float* __restrict__ nn,
                                                      float* __restrict__ outp){
  __shared__ __align__(16) char smem2[72704];
  const int t = threadIdx.x;
  const u32t* Sw = (const u32t*)SRCb;
  const u32t* Dw = (const u32t*)DSTb;
  const int w = t>>6, l = t&63;
  if(blockIdx.x >= NBIN){
    // ---------- edge path: bin-per-block, s-rows staged in LDS, 8 edges/wave ----------
    u32t* Sst  = (u32t*)smem2;            // 128 rows x 64 u32 = 32 KB
    u32t* Dst_ = (u32t*)(smem2+32768);    // 32 KB
    u64t* ent  = (u64t*)(smem2+65536);    // CAPE u64 = 7168 B
    int bin = blockIdx.x - NBIN;
    u32t base = ecoff[bin], cnt = ecoff[bin+1] - base;
    u32t cntp = (cnt+7)&~7u;
    for(u32t i=t;i<cntp;i+=256) ent[i] = (i<cnt)? ebuck[base+i] : 0ULL;
    for(int r=w; r<128; r+=4){
      int n = bin*128 + r;
      if(n < NNODE){
        Sst[r*64+l]  = Sw[(size_t)n*64 + l];
        Dst_[r*64+l] = Dw[(size_t)n*64 + l];
      }
    }
    __syncthreads();
    for(u32t i0 = (u32t)w*8; i0 < cnt; i0 += 32){
      u32t eq[8], dq[8], slq[8];
      #pragma unroll
      for(int q=0;q<8;q++){
        u64t en = ent[i0+q];                 // i0 multiple of 8, i0<cnt => i0+8<=cntp
        u32t lo = (u32t)en;
        eq[q]  = (u32t)(en>>32);
        dq[q]  = lo & 0x1FFFFu;
        slq[q] = (lo>>20)&127u;
      }
      float2 Ssq[8], Dsq[8], Sdq[8], Ddq[8]; float niq[8], noq[8];
      #pragma unroll
      for(int q=0;q<8;q++){
        Ssq[q] = up2(Sst[slq[q]*64 + l]);
        Dsq[q] = up2(Dst_[slq[q]*64 + l]);
        Sdq[q] = up2(Sw[(size_t)dq[q]*64 + l]);
        Ddq[q] = up2(Dw[(size_t)dq[q]*64 + l]);
        niq[q] = __builtin_nontemporal_load(&nin[(size_t)eq[q]*DOUTN + l]);
        noq[q] = __builtin_nontemporal_load(&nout[(size_t)eq[q]*DOUTN + l]);
      }
      #pragma unroll
      for(int q=0;q<8;q++){
        if(i0 + (u32t)q < cnt){
          size_t o = (size_t)eq[q]*DOUTN + l;
          float miu_in  = Ssq[q].x + Ddq[q].x, ls_in  = Ssq[q].y + Ddq[q].y;
          float miu_out = Sdq[q].x + Dsq[q].x, ls_out = Sdq[q].y + Dsq[q].y;
          __builtin_nontemporal_store(niq[q] * __expf(ls_in)  + miu_in,  &ein[o]);
          __builtin_nontemporal_store(noq[q] * __expf(ls_out) + miu_out, &eout[o]);
        }
      }
    }
    return;
  }
  // ---------- bi path: bin-per-block in-LDS CSR + gather + finalize ----------
  u64t* ebuf = (u64t*)smem2;               // CAPB u64 = 12288 B
  u32t* hist = (u32t*)(smem2+12288);
  u32t* offs = (u32t*)(smem2+12800);
  u32t* cur  = (u32t*)(smem2+13328);
  u32t* sc   = (u32t*)(smem2+13840);
  int bin = blockIdx.x;
  u32t base = bcoff[bin], cnt = bcoff[bin+1] - base;
  if(t<128) hist[t]=0;
  __syncthreads();
  for(u32t i=t;i<cnt;i+=256)
    atomicAdd(&hist[(u32t)(bbuck[base+i]>>20)&127u], 1u);
  __syncthreads();
  if(t<128) sc[t]=hist[t];
  __syncthreads();
  for(int off=1;off<128;off<<=1){
    u32t x=(t>=off&&t<128)?sc[t-off]:0u;
    __syncthreads();
    if(t<128) sc[t]+=x;
    __syncthreads();
  }
  if(t<128){ offs[t+1]=sc[t]; cur[t]=sc[t]-hist[t]; if(t==0) offs[0]=0u; }
  __syncthreads();
  for(u32t i=t;i<cnt;i+=256){
    u64t e = bbuck[base+i];
    u32t p = atomicAdd(&cur[(u32t)(e>>20)&127u], 1u);
    ebuf[p]=e;
  }
  __syncthreads();
  for(int idx=w; idx<128; idx+=4){
    int n = bin*128 + idx;
    if(n >= NNODE) continue;
    float2 S = up2(Sw[(size_t)n*64 + l]);
    u32t s0=offs[idx], cnt2=offs[idx+1]-s0;
    float nmiu=0.f, nvar=0.f;
    u32t nbr=(cnt2+3)&~3u;
    for(u32t j=0;j<nbr;j+=4){
      float2 Dq[4]; float vs[4];
      #pragma unroll
      for(int q=0;q<4;q++){
        u32t jj=j+q;
        u64t e=(jj<cnt2)? ebuf[s0+jj] : 0ULL;
        vs[q]=__uint_as_float((u32t)(e>>32));
        Dq[q]=up2(Dw[(size_t)(e&0x1FFFFu)*64 + l]);
      }
      #pragma unroll
      for(int q=0;q<4;q++){
        nmiu += vs[q]*(S.x+Dq[q].x);
        nvar += vs[q]*vs[q]*__expf(S.y+Dq[q].y);
      }
    }
    size_t o = (size_t)n*DOUTN + l;
    float nd = __builtin_nontemporal_load(&nn[o]);
    __builtin_nontemporal_store(nd*sqrtf(nvar) + nmiu, &outp[o]);  // exp(0.5*log v)==sqrt(v)
  }
}

extern "C" void kernel_launch(void* const* d_in, const int* in_sizes, int n_in,
                              void* d_out, int out_size, void* d_ws, size_t ws_size,
                              hipStream_t stream){
  const float* X    = (const float*)d_in[0];
  const float* Wg   = (const float*)d_in[1];
  const float* Wm   = (const float*)d_in[2];
  const float* Wsg  = (const float*)d_in[3];
  const float* gv   = (const float*)d_in[4];
  const float* bv   = (const float*)d_in[5];
  const float* nin  = (const float*)d_in[6];
  const float* nout = (const float*)d_in[7];
  const float* nnod = (const float*)d_in[8];
  const int*  gi   = (const int*)d_in[9];
  const int*  ed   = (const int*)d_in[10];
  const int*  be   = (const int*)d_in[11];

  // workspace (76.8 MB):
  //  [0,12.8M)          gbuck u64 (dead after gather)   -> phase2: DSTw bf16 [0,25.6M)
  //  [12.8M,38.4M)      xwb bf16 (dead after gather)    -> (tail of DSTw)
  //  [38.40M,+36K)      meta: gcnt|bcnt|ecnt|gcoff|gcur|bcoff|bcur|ecoff|ecur (4KB each)
  //  [38.44M,46.44M)    bbuck u64 (live until edgebi2)
  //  [46.44M,50.44M)    ebuck u64 (live until edgebi2)
  //  [51.2M,76.8M)      hiddenw -> in-place SRCw bf16 after gemm2
  char* ws = (char*)d_ws;
  u64t*  gbuck   = (u64t*)ws;
  u16t*  xwb     = (u16t*)(ws + 12800000);
  u32t*  gcnt_c  = (u32t*)(ws + 38400000);
  u32t*  bcnt_c  = (u32t*)(ws + 38404096);
  u32t*  ecnt_c  = (u32t*)(ws + 38408192);
  u32t*  gcoff   = (u32t*)(ws + 38412288);
  u32t*  gcur_   = (u32t*)(ws + 38416384);
  u32t*  bcoff   = (u32t*)(ws + 38420480);
  u32t*  bcur_   = (u32t*)(ws + 38424576);
  u32t*  ecoff   = (u32t*)(ws + 38428672);
  u32t*  ecur_   = (u32t*)(ws + 38432768);
  u64t*  bbuck   = (u64t*)(ws + 38440000);
  u64t*  ebuck   = (u64t*)(ws + 46440000);
  u32t*  hiddenw = (u32t*)(ws + 51200000);
  u16t*  SRCw    = (u16t*)hiddenw;
  u16t*  DSTw    = (u16t*)ws;

  float* out  = (float*)d_out;
  float* ein  = out + (size_t)NNODE*DOUTN;
  float* eout = ein + (size_t)EDIR*DOUTN;
  // weight-prep arrays in tail of d_out's node region; dead before edgebi2 overwrites
  u16t* Wg_pre = (u16t*)((char*)d_out + 25600000 - 131072);
  u16t* Wc_pre = Wg_pre + 32768;

  (void)hipMemsetAsync(gcnt_c, 0, 12288, stream);               // gcnt + bcnt + ecnt
  histprep_kernel   <<<KPART+256, 256, 0, stream>>>(gi, be, ed, gcnt_c, bcnt_c, ecnt_c,
                                                    Wg, Wm, Wsg, Wg_pre, Wc_pre);
  scan_coarse_kernel<<<3,         256, 0, stream>>>(gcnt_c, gcoff, gcur_, bcnt_c, bcoff, bcur_,
                                                    ecnt_c, ecoff, ecur_);
  partgemm1_kernel  <<<G64+KPART, 256, 0, stream>>>(X, Wg_pre, xwb,
                                                    gi, gv, be, bv, ed,
                                                    gcur_, gbuck, bcur_, bbuck, ecur_, ebuck);
  gcn_gather2_kernel<<<NBIN,      256, 0, stream>>>(xwb, gbuck, gcoff, hiddenw);
  gemm2_kernel      <<<G64,       256, 0, stream>>>(hiddenw, Wc_pre, DSTw);
  edgebi2_kernel    <<<2*NBIN,    256, 0, stream>>>(SRCw, DSTw, nin, nout,
                                                    ein, eout, bbuck, bcoff,
                                                    ebuck, ecoff, nnod, out);
}

// Round 18
// 404.155 us; speedup vs baseline: 1.1914x; 1.1914x over previous
//
#include <hip/hip_runtime.h>
#include <hip/hip_bf16.h>

typedef unsigned short u16t;
typedef unsigned int   u32t;
typedef unsigned long long u64t;

#define NNODE 100000
#define DIN   256
#define HIDN  128
#define DOUTN 64
#define NNZE  1600000
#define EDIR  500000
#define EBI   1000000
#define G64   1563           // ceil(NNODE/64)
#define NBIN  782            // ceil(NNODE/128), bin = key>>7
#define CH3   4096           // edges per partition block
#define K3G   391            // ceil(NNZE/CH3)
#define K3B   245            // ceil(EBI/CH3)
#define K3E   123            // ceil(EDIR/CH3)
#define KPART (K3G+K3B+K3E)  // 759 partition blocks
#define CAPG  2432           // gcn entries per bin cap
#define CAPB  1536           // bi entries per bin cap

typedef __attribute__((ext_vector_type(8))) short bf16x8;
typedef __attribute__((ext_vector_type(4))) float f32x4;
typedef __attribute__((ext_vector_type(4))) float f4v;

__device__ __forceinline__ u32t pk2bf(float a, float b){
  __hip_bfloat162 h = __float22bfloat162_rn(make_float2(a, b));
  union { __hip_bfloat162 h2; u32t u; } c; c.h2 = h; return c.u;
}
__device__ __forceinline__ u16t s2bf(float a){
  __hip_bfloat16 h = __float2bfloat16(a);
  union { __hip_bfloat16 h1; u16t u; } c; c.h1 = h; return c.u;
}
__device__ __forceinline__ float2 up2(u32t w){
  return make_float2(__uint_as_float(w<<16), __uint_as_float(w&0xFFFF0000u));
}

// ---------------- union: coarse histogram (3 streams) + weight prep ----------------
__global__ __launch_bounds__(256) void histprep_kernel(const int* __restrict__ gi,
                                                       const int* __restrict__ be,
                                                       const int* __restrict__ ed,
                                                       u32t* __restrict__ gcnt_c,
                                                       u32t* __restrict__ bcnt_c,
                                                       u32t* __restrict__ ecnt_c,
                                                       const float* __restrict__ Wg,
                                                       const float* __restrict__ Wm,
                                                       const float* __restrict__ Wsg,
                                                       u16t* __restrict__ Wg_pre,
                                                       u16t* __restrict__ Wc_pre){
  __shared__ u32t h[1024];
  int blk = blockIdx.x, t = threadIdx.x;
  if(blk >= KPART){
    int idx = (blk-KPART)*256 + t;              // 0..65535
    int e = idx & 7, l = (idx>>3) & 63, f = (idx>>9) & 63, sel = idx>>15;
    int k_in = ((e>>2)<<4) + ((l>>4)<<2) + (e&3);
    if(sel == 0){
      int ks = f>>3, nf = f&7;
      int k = ks*32 + k_in, n = nf*16 + (l&15);
      Wg_pre[idx] = s2bf(Wg[(size_t)k*HIDN + n]);
    } else {
      int ks = f>>4, nf = f&15;
      int k = ks*32 + k_in, c = nf*16 + (l&15);
      int half = c>>7, ci = c&127;
      const float* src = (ci&1) ? Wsg : Wm;
      Wc_pre[idx - 32768] = s2bf(src[(size_t)(half*128 + k)*DOUTN + (ci>>1)]);
    }
    return;
  }
  const int* keys; u32t* outc; int E, e0;
  if(blk < K3G)          { keys=gi;      outc=gcnt_c; E=NNZE; e0=blk*CH3; }
  else if(blk < K3G+K3B) { keys=be;      outc=bcnt_c; E=EBI;  e0=(blk-K3G)*CH3; }
  else                   { keys=ed+EDIR; outc=ecnt_c; E=EDIR; e0=(blk-K3G-K3B)*CH3; }  // key = d
  for(int i=t;i<1024;i+=256) h[i]=0;
  __syncthreads();
  for(int i=t;i<CH3;i+=256){
    int e=e0+i;
    if(e<E) atomicAdd(&h[(u32t)keys[e]>>7], 1u);
  }
  __syncthreads();
  for(int b=t;b<1024;b+=256){
    u32t c=h[b];
    if(c) atomicAdd(&outc[b], c);
  }
}

// ---------------- scan coarse counts -> offsets + cursors (3 blocks) ----------------
__global__ __launch_bounds__(256) void scan_coarse_kernel(u32t* __restrict__ gcnt_c,
                                                          u32t* __restrict__ gcoff,
                                                          u32t* __restrict__ gcur_,
                                                          u32t* __restrict__ bcnt_c,
                                                          u32t* __restrict__ bcoff,
                                                          u32t* __restrict__ bcur_,
                                                          u32t* __restrict__ ecnt_c,
                                                          u32t* __restrict__ ecoff,
                                                          u32t* __restrict__ ecur_){
  __shared__ u32t part[256];
  u32t *cnt, *coff, *cur;
  if(blockIdx.x==0)      { cnt=gcnt_c; coff=gcoff; cur=gcur_; }
  else if(blockIdx.x==1) { cnt=bcnt_c; coff=bcoff; cur=bcur_; }
  else                   { cnt=ecnt_c; coff=ecoff; cur=ecur_; }
  int t = threadIdx.x;
  u32t ch[4], s=0;
  #pragma unroll
  for(int j=0;j<4;j++){ int idx=t*4+j; ch[j] = (idx<NBIN)? cnt[idx] : 0u; s+=ch[j]; }
  part[t]=s; __syncthreads();
  for(int off=1;off<256;off<<=1){
    u32t x=(t>=off)?part[t-off]:0u;
    __syncthreads();
    part[t]+=x;
    __syncthreads();
  }
  u32t run=(t==0)?0u:part[t-1];
  #pragma unroll
  for(int j=0;j<4;j++){
    int idx=t*4+j;
    if(idx<NBIN){ coff[idx]=run; cur[idx]=run; run+=ch[j]; }
  }
  if(t==255) coff[NBIN]=part[255];
}

// ---------------- union: GEMM1 (blocks [0,G64)) + partition (3 streams, after) ----------------
__global__ __launch_bounds__(256) void partgemm1_kernel(const float* __restrict__ X,
                                                        const u16t* __restrict__ Wg_pre,
                                                        u16t* __restrict__ xwb,
                                                        const int* __restrict__ gi,
                                                        const float* __restrict__ gv,
                                                        const int* __restrict__ be,
                                                        const float* __restrict__ bv,
                                                        const int* __restrict__ ed,
                                                        u32t* __restrict__ gcur_,
                                                        u64t* __restrict__ gbuck,
                                                        u32t* __restrict__ bcur_,
                                                        u64t* __restrict__ bbuck,
                                                        u32t* __restrict__ ecur_,
                                                        u64t* __restrict__ ebuck){
  __shared__ __align__(16) char smem[50176];
  const int t = threadIdx.x;
  if(blockIdx.x < G64){
    // ---------------- GEMM1 path ----------------
    u16t* Xs = (u16t*)smem;                     // 32 KB, 8B-granule XOR-swizzled
    const int l = t & 63, w = t >> 6;
    const int row0 = blockIdx.x * 64;
    for(int i=0;i<16;i++){
      int m = w*16 + i;
      int mg = min(row0 + m, NNODE-1);
      f4v f = __builtin_nontemporal_load((const f4v*)&X[(size_t)mg*DIN + l*4]);
      u32t* p = (u32t*)&Xs[m*256 + ((l ^ (m&15))<<2)];
      p[0] = pk2bf(f[0], f[1]);
      p[1] = pk2bf(f[2], f[3]);
    }
    __syncthreads();
    f32x4 acc[8];
    #pragma unroll
    for(int nf=0;nf<8;nf++) acc[nf] = (f32x4)(0.f);
    const int lm = l & 15, l4 = l >> 4;
    const int mrow = w*16 + lm;
    #pragma unroll 1
    for(int ks=0; ks<8; ks++){
      int kg = ks*8 + l4;
      union { uint2 u2[2]; bf16x8 v; } a;
      a.u2[0] = *(const uint2*)&Xs[mrow*256 + ((kg     ^ lm)<<2)];
      a.u2[1] = *(const uint2*)&Xs[mrow*256 + (((kg+4) ^ lm)<<2)];
      #pragma unroll
      for(int nf=0;nf<8;nf++){
        union { uint4 u4; bf16x8 v; } b;
        b.u4 = *(const uint4*)&Wg_pre[(size_t)((ks*8+nf)*64 + l)*8];
        acc[nf] = __builtin_amdgcn_mfma_f32_16x16x32_bf16(a.v, b.v, acc[nf], 0, 0, 0);
      }
    }
    #pragma unroll
    for(int r=0;r<4;r++){
      int gr = row0 + w*16 + l4*4 + r;
      if(gr < NNODE){
        #pragma unroll
        for(int nf=0;nf<8;nf++)
          xwb[(size_t)gr*HIDN + nf*16 + lm] = s2bf(acc[nf][r]);
      }
    }
    return;
  }
  // ---------------- partition path (3 streams) ----------------
  u32t* hist = (u32t*)smem;
  u32t* scn  = (u32t*)(smem+4096);
  u32t* prt  = (u32t*)(smem+8192);
  u64t* ebuf = (u64t*)(smem+9216);
  u16t* bins = (u16t*)(smem+41984);
  int blk = blockIdx.x - G64;
  const int *keys, *pay; const float* val; u32t* cursor; u64t* buck; int E, e0; bool eStream=false;
  if(blk < K3G)          { keys=gi;      pay=gi+NNZE; val=gv; cursor=gcur_; buck=gbuck; E=NNZE; e0=blk*CH3; }
  else if(blk < K3G+K3B) { keys=be;      pay=be+EBI;  val=bv; cursor=bcur_; buck=bbuck; E=EBI;  e0=(blk-K3G)*CH3; }
  else                   { keys=ed+EDIR; pay=ed;      val=0;  cursor=ecur_; buck=ebuck; E=EDIR; e0=(blk-K3G-K3B)*CH3; eStream=true; }
  for(int i=t;i<1024;i+=256) hist[i]=0;
  __syncthreads();
  for(int i=t;i<CH3;i+=256){
    int e=e0+i;
    if(e<E) atomicAdd(&hist[(u32t)keys[e]>>7], 1u);
  }
  __syncthreads();
  u32t ch[4], s=0;
  #pragma unroll
  for(int j=0;j<4;j++){ ch[j]=hist[t*4+j]; s+=ch[j]; }
  prt[t]=s; __syncthreads();
  for(int off=1;off<256;off<<=1){
    u32t x=(t>=off)?prt[t-off]:0u;
    __syncthreads();
    prt[t]+=x;
    __syncthreads();
  }
  u32t run=(t==0)?0u:prt[t-1];
  #pragma unroll
  for(int j=0;j<4;j++){ scn[t*4+j]=run; run+=ch[j]; }
  __syncthreads();
  for(int i=t;i<1024;i+=256) hist[i]=scn[i];   // hist becomes local cursor
  __syncthreads();
  for(int i=t;i<CH3;i+=256){
    int e=e0+i;
    if(e<E){
      int k = keys[e];
      u32t b = (u32t)k>>7;
      u32t p = atomicAdd(&hist[b],1u);
      u64t hi = eStream ? (u64t)(u32t)e : (u64t)__float_as_uint(val[e]);
      u64t ent = (u64t)((u32t)pay[e] | (((u32t)k&127u)<<20)) | (hi<<32);
      ebuf[p]=ent; bins[p]=(u16t)b;
    }
  }
  __syncthreads();
  for(int b=t;b<1024;b+=256){
    u32t c = hist[b]-scn[b];
    u32t bs = c ? atomicAdd(&cursor[b], c) : 0u;
    hist[b] = bs;
  }
  __syncthreads();
  int totalValid = prt[255];
  for(int i=t;i<totalValid;i+=256){
    u32t b = bins[i];
    buck[ (size_t)hist[b] + (u32t)i - scn[b] ] = ebuf[i];
  }
}

// ---------------- GCN gather: bin-per-block, in-LDS CSR + gather (8x MLP) ----------------
__global__ __launch_bounds__(256) void gcn_gather2_kernel(const u16t* __restrict__ xwb,
                                                          const u64t* __restrict__ gbuck,
                                                          const u32t* __restrict__ gcoff,
                                                          u32t* __restrict__ hiddenw){
  __shared__ u64t ebuf[CAPG];
  __shared__ u32t hist[128], offs[129], cur[128], sc[128];
  int bin = blockIdx.x, t = threadIdx.x;
  u32t base = gcoff[bin], cnt = gcoff[bin+1] - base;
  if(t<128) hist[t]=0;
  __syncthreads();
  for(u32t i=t;i<cnt;i+=256)
    atomicAdd(&hist[(u32t)(gbuck[base+i]>>20)&127u], 1u);
  __syncthreads();
  if(t<128) sc[t]=hist[t];
  __syncthreads();
  for(int off=1;off<128;off<<=1){
    u32t x=(t>=off&&t<128)?sc[t-off]:0u;
    __syncthreads();
    if(t<128) sc[t]+=x;
    __syncthreads();
  }
  if(t<128){ offs[t+1]=sc[t]; cur[t]=sc[t]-hist[t]; if(t==0) offs[0]=0u; }
  __syncthreads();
  for(u32t i=t;i<cnt;i+=256){
    u64t e = gbuck[base+i];
    u32t p = atomicAdd(&cur[(u32t)(e>>20)&127u], 1u);
    ebuf[p]=e;
  }
  __syncthreads();
  int w=t>>6, l=t&63;
  const u32t* xww=(const u32t*)xwb;
  for(int idx=w; idx<128; idx+=4){
    int n = bin*128 + idx;
    if(n >= NNODE) continue;
    u32t s0=offs[idx], cnt2=offs[idx+1]-s0;
    float acc0=0.f, acc1=0.f;
    u32t nbr=(cnt2+7)&~7u;
    for(u32t j=0;j<nbr;j+=8){
      float2 xs[8]; float vs[8];
      #pragma unroll
      for(int q=0;q<8;q++){
        u32t jj=j+q;
        u64t e=(jj<cnt2)? ebuf[s0+jj] : 0ULL;
        vs[q]=__uint_as_float((u32t)(e>>32));
        xs[q]=up2(xww[(size_t)(e&0x1FFFFu)*64 + l]);
      }
      #pragma unroll
      for(int q=0;q<8;q++){ acc0+=vs[q]*xs[q].x; acc1+=vs[q]*xs[q].y; }
    }
    hiddenw[(size_t)n*64 + l] = pk2bf(acc0, acc1);
  }
}

// ---------------- GEMM2 (MFMA): SRCw (in-place over hiddenw) + DSTw ----------------
__global__ __launch_bounds__(256) void gemm2_kernel(u32t* __restrict__ hiddenw,
                                                    const u16t* __restrict__ Wc_pre,
                                                    u16t* __restrict__ DSTw){
  __shared__ __align__(16) u16t Hs[64*128];   // 16 KB
  const int t = threadIdx.x, l = t & 63, w = t >> 6;
  const int row0 = blockIdx.x * 64;
  for(int i=0;i<16;i++){
    int m = w*16 + i;
    int mg = min(row0 + m, NNODE-1);
    u32t v = hiddenw[(size_t)mg*64 + l];
    *(u32t*)&Hs[m*128 + (((l>>1) ^ (m&15))<<2) + ((l&1)<<1)] = v;
  }
  __syncthreads();
  f32x4 acc[16];
  #pragma unroll
  for(int nf=0;nf<16;nf++) acc[nf] = (f32x4)(0.f);
  const int lm = l & 15, l4 = l >> 4;
  const int mrow = w*16 + lm;
  #pragma unroll 1
  for(int ks=0; ks<4; ks++){
    int kg = ks*8 + l4;
    union { uint2 u2[2]; bf16x8 v; } a;
    a.u2[0] = *(const uint2*)&Hs[mrow*128 + ((kg     ^ lm)<<2)];
    a.u2[1] = *(const uint2*)&Hs[mrow*128 + (((kg+4) ^ lm)<<2)];
    #pragma unroll
    for(int nf=0;nf<16;nf++){
      union { uint4 u4; bf16x8 v; } b;
      b.u4 = *(const uint4*)&Wc_pre[(size_t)((ks*16+nf)*64 + l)*8];
      acc[nf] = __builtin_amdgcn_mfma_f32_16x16x32_bf16(a.v, b.v, acc[nf], 0, 0, 0);
    }
  }
  u16t* SRCw = (u16t*)hiddenw;   // in-place: this block's rows were staged above
  #pragma unroll
  for(int r=0;r<4;r++){
    int gr = row0 + w*16 + l4*4 + r;
    if(gr < NNODE){
      #pragma unroll
      for(int nf=0;nf<8;nf++)
        SRCw[(size_t)gr*HIDN + nf*16 + lm] = s2bf(acc[nf][r]);
      #pragma unroll
      for(int nf=8;nf<16;nf++)
        DSTw[(size_t)gr*HIDN + (nf-8)*16 + lm] = s2bf(acc[nf][r]);
    }
  }
}

// ---------------- union kernel: bi bins [0,NBIN) + d-binned edge heads [NBIN,2*NBIN) ----------------
__global__ __launch_bounds__(256) void edgebi2_kernel(const u16t* __restrict__ SRCb,
                                                      const u16t* __restrict__ DSTb,
                                                      const float* __restrict__ nin,
                                                      const float* __restrict__ nout,
                                                      float* __restrict__ ein,
                                                      float* __restrict__ eout,
                                                      const u64t* __restrict__ bbuck,
                                                      const u32t* __restrict__ bcoff,
                                                      const u64t* __restrict__ ebuck,
                                                      const u32t* __restrict__ ecoff,
                                                      const float* __restrict__ nn,
                                                      float* __restrict__ outp){
  __shared__ u64t ebuf[CAPB];
  __shared__ u32t hist[128], offs[129], cur[128], sc[128];
  const int t = threadIdx.x;
  const u32t* Sw = (const u32t*)SRCb;
  const u32t* Dw = (const u32t*)DSTb;
  const int w = t>>6, l = t&63;
  if(blockIdx.x >= NBIN){
    // ---------- edge path: d-binned, 8 edges/wave, global gathers (d-rows L2-hot) ----------
    int bin = blockIdx.x - NBIN;
    u32t base = ecoff[bin], cnt = ecoff[bin+1] - base;
    if(cnt == 0) return;
    for(u32t i0 = (u32t)w*8; i0 < cnt; i0 += 32){
      u32t eq[8], sq[8], dq[8];
      #pragma unroll
      for(int q=0;q<8;q++){
        u32t ii = min(i0+(u32t)q, cnt-1u);
        u64t en = ebuck[base+ii];
        u32t lo = (u32t)en;
        eq[q] = (u32t)(en>>32);
        sq[q] = lo & 0x1FFFFu;
        dq[q] = (u32t)bin*128u + ((lo>>20)&127u);
      }
      float2 Ss[8], Ds[8], Sd[8], Dd[8];
      float ni[8], no[8];
      #pragma unroll
      for(int q=0;q<8;q++){
        Ss[q] = up2(Sw[(size_t)sq[q]*64 + l]);
        Ds[q] = up2(Dw[(size_t)sq[q]*64 + l]);
        Sd[q] = up2(Sw[(size_t)dq[q]*64 + l]);
        Dd[q] = up2(Dw[(size_t)dq[q]*64 + l]);
        ni[q] = __builtin_nontemporal_load(&nin[(size_t)eq[q]*DOUTN + l]);
        no[q] = __builtin_nontemporal_load(&nout[(size_t)eq[q]*DOUTN + l]);
      }
      #pragma unroll
      for(int q=0;q<8;q++){
        if(i0 + (u32t)q < cnt){
          size_t o = (size_t)eq[q]*DOUTN + l;
          float miu_in  = Ss[q].x + Dd[q].x, ls_in  = Ss[q].y + Dd[q].y;
          float miu_out = Sd[q].x + Ds[q].x, ls_out = Sd[q].y + Ds[q].y;
          __builtin_nontemporal_store(ni[q] * __expf(ls_in)  + miu_in,  &ein[o]);
          __builtin_nontemporal_store(no[q] * __expf(ls_out) + miu_out, &eout[o]);
        }
      }
    }
    return;
  }
  // ---------- bi path: bin-per-block in-LDS CSR + gather + finalize ----------
  int bin = blockIdx.x;
  u32t base = bcoff[bin], cnt = bcoff[bin+1] - base;
  if(t<128) hist[t]=0;
  __syncthreads();
  for(u32t i=t;i<cnt;i+=256)
    atomicAdd(&hist[(u32t)(bbuck[base+i]>>20)&127u], 1u);
  __syncthreads();
  if(t<128) sc[t]=hist[t];
  __syncthreads();
  for(int off=1;off<128;off<<=1){
    u32t x=(t>=off&&t<128)?sc[t-off]:0u;
    __syncthreads();
    if(t<128) sc[t]+=x;
    __syncthreads();
  }
  if(t<128){ offs[t+1]=sc[t]; cur[t]=sc[t]-hist[t]; if(t==0) offs[0]=0u; }
  __syncthreads();
  for(u32t i=t;i<cnt;i+=256){
    u64t e = bbuck[base+i];
    u32t p = atomicAdd(&cur[(u32t)(e>>20)&127u], 1u);
    ebuf[p]=e;
  }
  __syncthreads();
  for(int idx=w; idx<128; idx+=4){
    int n = bin*128 + idx;
    if(n >= NNODE) continue;
    float2 S = up2(Sw[(size_t)n*64 + l]);
    u32t s0=offs[idx], cnt2=offs[idx+1]-s0;
    float nmiu=0.f, nvar=0.f;
    u32t nbr=(cnt2+3)&~3u;
    for(u32t j=0;j<nbr;j+=4){
      float2 Dq[4]; float vs[4];
      #pragma unroll
      for(int q=0;q<4;q++){
        u32t jj=j+q;
        u64t e=(jj<cnt2)? ebuf[s0+jj] : 0ULL;
        vs[q]=__uint_as_float((u32t)(e>>32));
        Dq[q]=up2(Dw[(size_t)(e&0x1FFFFu)*64 + l]);
      }
      #pragma unroll
      for(int q=0;q<4;q++){
        nmiu += vs[q]*(S.x+Dq[q].x);
        nvar += vs[q]*vs[q]*__expf(S.y+Dq[q].y);
      }
    }
    size_t o = (size_t)n*DOUTN + l;
    float nd = __builtin_nontemporal_load(&nn[o]);
    __builtin_nontemporal_store(nd*sqrtf(nvar) + nmiu, &outp[o]);  // exp(0.5*log v)==sqrt(v)
  }
}

extern "C" void kernel_launch(void* const* d_in, const int* in_sizes, int n_in,
                              void* d_out, int out_size, void* d_ws, size_t ws_size,
                              hipStream_t stream){
  const float* X    = (const float*)d_in[0];
  const float* Wg   = (const float*)d_in[1];
  const float* Wm   = (const float*)d_in[2];
  const float* Wsg  = (const float*)d_in[3];
  const float* gv   = (const float*)d_in[4];
  const float* bv   = (const float*)d_in[5];
  const float* nin  = (const float*)d_in[6];
  const float* nout = (const float*)d_in[7];
  const float* nnod = (const float*)d_in[8];
  const int*  gi   = (const int*)d_in[9];
  const int*  ed   = (const int*)d_in[10];
  const int*  be   = (const int*)d_in[11];

  // workspace (76.8 MB):
  //  [0,12.8M)          gbuck u64 (dead after gather)   -> phase2: DSTw bf16 [0,25.6M)
  //  [12.8M,38.4M)      xwb bf16 (dead after gather)    -> (tail of DSTw)
  //  [38.40M,+36K)      meta: gcnt|bcnt|ecnt|gcoff|gcur|bcoff|bcur|ecoff|ecur (4KB each)
  //  [38.44M,46.44M)    bbuck u64 (live until edgebi2)
  //  [46.44M,50.44M)    ebuck u64 (live until edgebi2)
  //  [51.2M,76.8M)      hiddenw -> in-place SRCw bf16 after gemm2
  char* ws = (char*)d_ws;
  u64t*  gbuck   = (u64t*)ws;
  u16t*  xwb     = (u16t*)(ws + 12800000);
  u32t*  gcnt_c  = (u32t*)(ws + 38400000);
  u32t*  bcnt_c  = (u32t*)(ws + 38404096);
  u32t*  ecnt_c  = (u32t*)(ws + 38408192);
  u32t*  gcoff   = (u32t*)(ws + 38412288);
  u32t*  gcur_   = (u32t*)(ws + 38416384);
  u32t*  bcoff   = (u32t*)(ws + 38420480);
  u32t*  bcur_   = (u32t*)(ws + 38424576);
  u32t*  ecoff   = (u32t*)(ws + 38428672);
  u32t*  ecur_   = (u32t*)(ws + 38432768);
  u64t*  bbuck   = (u64t*)(ws + 38440000);
  u64t*  ebuck   = (u64t*)(ws + 46440000);
  u32t*  hiddenw = (u32t*)(ws + 51200000);
  u16t*  SRCw    = (u16t*)hiddenw;
  u16t*  DSTw    = (u16t*)ws;

  float* out  = (float*)d_out;
  float* ein  = out + (size_t)NNODE*DOUTN;
  float* eout = ein + (size_t)EDIR*DOUTN;
  // weight-prep arrays in tail of d_out's node region; dead before edgebi2 overwrites
  u16t* Wg_pre = (u16t*)((char*)d_out + 25600000 - 131072);
  u16t* Wc_pre = Wg_pre + 32768;

  (void)hipMemsetAsync(gcnt_c, 0, 12288, stream);               // gcnt + bcnt + ecnt
  histprep_kernel   <<<KPART+256, 256, 0, stream>>>(gi, be, ed, gcnt_c, bcnt_c, ecnt_c,
                                                    Wg, Wm, Wsg, Wg_pre, Wc_pre);
  scan_coarse_kernel<<<3,         256, 0, stream>>>(gcnt_c, gcoff, gcur_, bcnt_c, bcoff, bcur_,
                                                    ecnt_c, ecoff, ecur_);
  partgemm1_kernel  <<<G64+KPART, 256, 0, stream>>>(X, Wg_pre, xwb,
                                                    gi, gv, be, bv, ed,
                                                    gcur_, gbuck, bcur_, bbuck, ecur_, ebuck);
  gcn_gather2_kernel<<<NBIN,      256, 0, stream>>>(xwb, gbuck, gcoff, hiddenw);
  gemm2_kernel      <<<G64,       256, 0, stream>>>(hiddenw, Wc_pre, DSTw);
  edgebi2_kernel    <<<2*NBIN,    256, 0, stream>>>(SRCw, DSTw, nin, nout,
                                                    ein, eout, bbuck, bcoff,
                                                    ebuck, ecoff, nnod, out);
}

// Round 19
// 380.529 us; speedup vs baseline: 1.2653x; 1.0621x over previous
//
#include <hip/hip_runtime.h>
#include <hip/hip_bf16.h>

typedef unsigned short u16t;
typedef unsigned int   u32t;
typedef unsigned long long u64t;

#define NNODE 100000
#define DIN   256
#define HIDN  128
#define DOUTN 64
#define NNZE  1600000
#define EDIR  500000
#define EBI   1000000
#define G64   1563           // ceil(NNODE/64)
#define NBIN  782            // ceil(NNODE/128), bin = key>>7
#define CH3   4096           // edges per partition block
#define K3G   391            // ceil(NNZE/CH3)
#define K3B   245            // ceil(EBI/CH3)
#define K3E   123            // ceil(EDIR/CH3)
#define KPART (K3G+K3B+K3E)  // 759 partition blocks
#define CAPG  2432           // gcn entries per bin cap
#define CAPB  1536           // bi entries per bin cap
#define EBLK  15625          // EDIR/32: flat edge blocks (8 edges/wave, 4 waves)

typedef __attribute__((ext_vector_type(8))) short bf16x8;
typedef __attribute__((ext_vector_type(4))) float f32x4;
typedef __attribute__((ext_vector_type(4))) float f4v;

__device__ __forceinline__ u32t pk2bf(float a, float b){
  __hip_bfloat162 h = __float22bfloat162_rn(make_float2(a, b));
  union { __hip_bfloat162 h2; u32t u; } c; c.h2 = h; return c.u;
}
__device__ __forceinline__ u16t s2bf(float a){
  __hip_bfloat16 h = __float2bfloat16(a);
  union { __hip_bfloat16 h1; u16t u; } c; c.h1 = h; return c.u;
}
__device__ __forceinline__ float2 up2(u32t w){
  return make_float2(__uint_as_float(w<<16), __uint_as_float(w&0xFFFF0000u));
}

// ---------------- union: coarse histogram (3 streams) + weight prep ----------------
__global__ __launch_bounds__(256) void histprep_kernel(const int* __restrict__ gi,
                                                       const int* __restrict__ be,
                                                       const int* __restrict__ ed,
                                                       u32t* __restrict__ gcnt_c,
                                                       u32t* __restrict__ bcnt_c,
                                                       u32t* __restrict__ ecnt_c,
                                                       const float* __restrict__ Wg,
                                                       const float* __restrict__ Wm,
                                                       const float* __restrict__ Wsg,
                                                       u16t* __restrict__ Wg_pre,
                                                       u16t* __restrict__ Wc_pre){
  __shared__ u32t h[1024];
  int blk = blockIdx.x, t = threadIdx.x;
  if(blk >= KPART){
    int idx = (blk-KPART)*256 + t;              // 0..65535
    int e = idx & 7, l = (idx>>3) & 63, f = (idx>>9) & 63, sel = idx>>15;
    int k_in = ((e>>2)<<4) + ((l>>4)<<2) + (e&3);
    if(sel == 0){
      int ks = f>>3, nf = f&7;
      int k = ks*32 + k_in, n = nf*16 + (l&15);
      Wg_pre[idx] = s2bf(Wg[(size_t)k*HIDN + n]);
    } else {
      int ks = f>>4, nf = f&15;
      int k = ks*32 + k_in, c = nf*16 + (l&15);
      int half = c>>7, ci = c&127;
      const float* src = (ci&1) ? Wsg : Wm;
      Wc_pre[idx - 32768] = s2bf(src[(size_t)(half*128 + k)*DOUTN + (ci>>1)]);
    }
    return;
  }
  const int* keys; u32t* outc; int E, e0;
  if(blk < K3G)          { keys=gi;      outc=gcnt_c; E=NNZE; e0=blk*CH3; }
  else if(blk < K3G+K3B) { keys=be;      outc=bcnt_c; E=EBI;  e0=(blk-K3G)*CH3; }
  else                   { keys=ed+EDIR; outc=ecnt_c; E=EDIR; e0=(blk-K3G-K3B)*CH3; }  // key = d
  for(int i=t;i<1024;i+=256) h[i]=0;
  __syncthreads();
  for(int i=t;i<CH3;i+=256){
    int e=e0+i;
    if(e<E) atomicAdd(&h[(u32t)keys[e]>>7], 1u);
  }
  __syncthreads();
  for(int b=t;b<1024;b+=256){
    u32t c=h[b];
    if(c) atomicAdd(&outc[b], c);
  }
}

// ---------------- scan coarse counts -> offsets + cursors (3 blocks) ----------------
__global__ __launch_bounds__(256) void scan_coarse_kernel(u32t* __restrict__ gcnt_c,
                                                          u32t* __restrict__ gcoff,
                                                          u32t* __restrict__ gcur_,
                                                          u32t* __restrict__ bcnt_c,
                                                          u32t* __restrict__ bcoff,
                                                          u32t* __restrict__ bcur_,
                                                          u32t* __restrict__ ecnt_c,
                                                          u32t* __restrict__ ecoff,
                                                          u32t* __restrict__ ecur_){
  __shared__ u32t part[256];
  u32t *cnt, *coff, *cur;
  if(blockIdx.x==0)      { cnt=gcnt_c; coff=gcoff; cur=gcur_; }
  else if(blockIdx.x==1) { cnt=bcnt_c; coff=bcoff; cur=bcur_; }
  else                   { cnt=ecnt_c; coff=ecoff; cur=ecur_; }
  int t = threadIdx.x;
  u32t ch[4], s=0;
  #pragma unroll
  for(int j=0;j<4;j++){ int idx=t*4+j; ch[j] = (idx<NBIN)? cnt[idx] : 0u; s+=ch[j]; }
  part[t]=s; __syncthreads();
  for(int off=1;off<256;off<<=1){
    u32t x=(t>=off)?part[t-off]:0u;
    __syncthreads();
    part[t]+=x;
    __syncthreads();
  }
  u32t run=(t==0)?0u:part[t-1];
  #pragma unroll
  for(int j=0;j<4;j++){
    int idx=t*4+j;
    if(idx<NBIN){ coff[idx]=run; cur[idx]=run; run+=ch[j]; }
  }
  if(t==255) coff[NBIN]=part[255];
}

// ---------------- union: GEMM1 (blocks [0,G64)) + partition (3 streams, after) ----------------
__global__ __launch_bounds__(256) void partgemm1_kernel(const float* __restrict__ X,
                                                        const u16t* __restrict__ Wg_pre,
                                                        u16t* __restrict__ xwb,
                                                        const int* __restrict__ gi,
                                                        const float* __restrict__ gv,
                                                        const int* __restrict__ be,
                                                        const float* __restrict__ bv,
                                                        const int* __restrict__ ed,
                                                        u32t* __restrict__ gcur_,
                                                        u64t* __restrict__ gbuck,
                                                        u32t* __restrict__ bcur_,
                                                        u64t* __restrict__ bbuck,
                                                        u32t* __restrict__ ecur_,
                                                        u64t* __restrict__ ebuck){
  __shared__ __align__(16) char smem[50176];
  const int t = threadIdx.x;
  if(blockIdx.x < G64){
    // ---------------- GEMM1 path ----------------
    u16t* Xs = (u16t*)smem;                     // 32 KB, 8B-granule XOR-swizzled
    const int l = t & 63, w = t >> 6;
    const int row0 = blockIdx.x * 64;
    for(int i=0;i<16;i++){
      int m = w*16 + i;
      int mg = min(row0 + m, NNODE-1);
      f4v f = __builtin_nontemporal_load((const f4v*)&X[(size_t)mg*DIN + l*4]);
      u32t* p = (u32t*)&Xs[m*256 + ((l ^ (m&15))<<2)];
      p[0] = pk2bf(f[0], f[1]);
      p[1] = pk2bf(f[2], f[3]);
    }
    __syncthreads();
    f32x4 acc[8];
    #pragma unroll
    for(int nf=0;nf<8;nf++) acc[nf] = (f32x4)(0.f);
    const int lm = l & 15, l4 = l >> 4;
    const int mrow = w*16 + lm;
    #pragma unroll 1
    for(int ks=0; ks<8; ks++){
      int kg = ks*8 + l4;
      union { uint2 u2[2]; bf16x8 v; } a;
      a.u2[0] = *(const uint2*)&Xs[mrow*256 + ((kg     ^ lm)<<2)];
      a.u2[1] = *(const uint2*)&Xs[mrow*256 + (((kg+4) ^ lm)<<2)];
      #pragma unroll
      for(int nf=0;nf<8;nf++){
        union { uint4 u4; bf16x8 v; } b;
        b.u4 = *(const uint4*)&Wg_pre[(size_t)((ks*8+nf)*64 + l)*8];
        acc[nf] = __builtin_amdgcn_mfma_f32_16x16x32_bf16(a.v, b.v, acc[nf], 0, 0, 0);
      }
    }
    #pragma unroll
    for(int r=0;r<4;r++){
      int gr = row0 + w*16 + l4*4 + r;
      if(gr < NNODE){
        #pragma unroll
        for(int nf=0;nf<8;nf++)
          xwb[(size_t)gr*HIDN + nf*16 + lm] = s2bf(acc[nf][r]);
      }
    }
    return;
  }
  // ---------------- partition path (3 streams) ----------------
  u32t* hist = (u32t*)smem;
  u32t* scn  = (u32t*)(smem+4096);
  u32t* prt  = (u32t*)(smem+8192);
  u64t* ebuf = (u64t*)(smem+9216);
  u16t* bins = (u16t*)(smem+41984);
  int blk = blockIdx.x - G64;
  const int *keys, *pay; const float* val; u32t* cursor; u64t* buck; int E, e0; bool eStream=false;
  if(blk < K3G)          { keys=gi;      pay=gi+NNZE; val=gv; cursor=gcur_; buck=gbuck; E=NNZE; e0=blk*CH3; }
  else if(blk < K3G+K3B) { keys=be;      pay=be+EBI;  val=bv; cursor=bcur_; buck=bbuck; E=EBI;  e0=(blk-K3G)*CH3; }
  else                   { keys=ed+EDIR; pay=ed;      val=0;  cursor=ecur_; buck=ebuck; E=EDIR; e0=(blk-K3G-K3B)*CH3; eStream=true; }
  for(int i=t;i<1024;i+=256) hist[i]=0;
  __syncthreads();
  for(int i=t;i<CH3;i+=256){
    int e=e0+i;
    if(e<E) atomicAdd(&hist[(u32t)keys[e]>>7], 1u);
  }
  __syncthreads();
  u32t ch[4], s=0;
  #pragma unroll
  for(int j=0;j<4;j++){ ch[j]=hist[t*4+j]; s+=ch[j]; }
  prt[t]=s; __syncthreads();
  for(int off=1;off<256;off<<=1){
    u32t x=(t>=off)?prt[t-off]:0u;
    __syncthreads();
    prt[t]+=x;
    __syncthreads();
  }
  u32t run=(t==0)?0u:prt[t-1];
  #pragma unroll
  for(int j=0;j<4;j++){ scn[t*4+j]=run; run+=ch[j]; }
  __syncthreads();
  for(int i=t;i<1024;i+=256) hist[i]=scn[i];   // hist becomes local cursor
  __syncthreads();
  for(int i=t;i<CH3;i+=256){
    int e=e0+i;
    if(e<E){
      int k = keys[e];
      u32t b = (u32t)k>>7;
      u32t p = atomicAdd(&hist[b],1u);
      u64t ent;
      if(eStream){
        // s (17b) | d (17b, bits 17..33) | e (19b, bits 34..52)
        ent = (u64t)(u32t)pay[e] | ((u64t)(u32t)k<<17) | ((u64t)(u32t)e<<34);
      } else {
        ent = (u64t)((u32t)pay[e] | (((u32t)k&127u)<<20)) | ((u64t)__float_as_uint(val[e])<<32);
      }
      ebuf[p]=ent; bins[p]=(u16t)b;
    }
  }
  __syncthreads();
  for(int b=t;b<1024;b+=256){
    u32t c = hist[b]-scn[b];
    u32t bs = c ? atomicAdd(&cursor[b], c) : 0u;
    hist[b] = bs;
  }
  __syncthreads();
  int totalValid = prt[255];
  for(int i=t;i<totalValid;i+=256){
    u32t b = bins[i];
    buck[ (size_t)hist[b] + (u32t)i - scn[b] ] = ebuf[i];
  }
}

// ---------------- GCN gather: bin-per-block, in-LDS CSR + gather (8x MLP) ----------------
__global__ __launch_bounds__(256) void gcn_gather2_kernel(const u16t* __restrict__ xwb,
                                                          const u64t* __restrict__ gbuck,
                                                          const u32t* __restrict__ gcoff,
                                                          u32t* __restrict__ hiddenw){
  __shared__ u64t ebuf[CAPG];
  __shared__ u32t hist[128], offs[129], cur[128], sc[128];
  int bin = blockIdx.x, t = threadIdx.x;
  u32t base = gcoff[bin], cnt = gcoff[bin+1] - base;
  if(t<128) hist[t]=0;
  __syncthreads();
  for(u32t i=t;i<cnt;i+=256)
    atomicAdd(&hist[(u32t)(gbuck[base+i]>>20)&127u], 1u);
  __syncthreads();
  if(t<128) sc[t]=hist[t];
  __syncthreads();
  for(int off=1;off<128;off<<=1){
    u32t x=(t>=off&&t<128)?sc[t-off]:0u;
    __syncthreads();
    if(t<128) sc[t]+=x;
    __syncthreads();
  }
  if(t<128){ offs[t+1]=sc[t]; cur[t]=sc[t]-hist[t]; if(t==0) offs[0]=0u; }
  __syncthreads();
  for(u32t i=t;i<cnt;i+=256){
    u64t e = gbuck[base+i];
    u32t p = atomicAdd(&cur[(u32t)(e>>20)&127u], 1u);
    ebuf[p]=e;
  }
  __syncthreads();
  int w=t>>6, l=t&63;
  const u32t* xww=(const u32t*)xwb;
  for(int idx=w; idx<128; idx+=4){
    int n = bin*128 + idx;
    if(n >= NNODE) continue;
    u32t s0=offs[idx], cnt2=offs[idx+1]-s0;
    float acc0=0.f, acc1=0.f;
    u32t nbr=(cnt2+7)&~7u;
    for(u32t j=0;j<nbr;j+=8){
      float2 xs[8]; float vs[8];
      #pragma unroll
      for(int q=0;q<8;q++){
        u32t jj=j+q;
        u64t e=(jj<cnt2)? ebuf[s0+jj] : 0ULL;
        vs[q]=__uint_as_float((u32t)(e>>32));
        xs[q]=up2(xww[(size_t)(e&0x1FFFFu)*64 + l]);
      }
      #pragma unroll
      for(int q=0;q<8;q++){ acc0+=vs[q]*xs[q].x; acc1+=vs[q]*xs[q].y; }
    }
    hiddenw[(size_t)n*64 + l] = pk2bf(acc0, acc1);
  }
}

// ---------------- GEMM2 (MFMA): SRCw (in-place over hiddenw) + DSTw ----------------
__global__ __launch_bounds__(256) void gemm2_kernel(u32t* __restrict__ hiddenw,
                                                    const u16t* __restrict__ Wc_pre,
                                                    u16t* __restrict__ DSTw){
  __shared__ __align__(16) u16t Hs[64*128];   // 16 KB
  const int t = threadIdx.x, l = t & 63, w = t >> 6;
  const int row0 = blockIdx.x * 64;
  for(int i=0;i<16;i++){
    int m = w*16 + i;
    int mg = min(row0 + m, NNODE-1);
    u32t v = hiddenw[(size_t)mg*64 + l];
    *(u32t*)&Hs[m*128 + (((l>>1) ^ (m&15))<<2) + ((l&1)<<1)] = v;
  }
  __syncthreads();
  f32x4 acc[16];
  #pragma unroll
  for(int nf=0;nf<16;nf++) acc[nf] = (f32x4)(0.f);
  const int lm = l & 15, l4 = l >> 4;
  const int mrow = w*16 + lm;
  #pragma unroll 1
  for(int ks=0; ks<4; ks++){
    int kg = ks*8 + l4;
    union { uint2 u2[2]; bf16x8 v; } a;
    a.u2[0] = *(const uint2*)&Hs[mrow*128 + ((kg     ^ lm)<<2)];
    a.u2[1] = *(const uint2*)&Hs[mrow*128 + (((kg+4) ^ lm)<<2)];
    #pragma unroll
    for(int nf=0;nf<16;nf++){
      union { uint4 u4; bf16x8 v; } b;
      b.u4 = *(const uint4*)&Wc_pre[(size_t)((ks*16+nf)*64 + l)*8];
      acc[nf] = __builtin_amdgcn_mfma_f32_16x16x32_bf16(a.v, b.v, acc[nf], 0, 0, 0);
    }
  }
  u16t* SRCw = (u16t*)hiddenw;   // in-place: this block's rows were staged above
  #pragma unroll
  for(int r=0;r<4;r++){
    int gr = row0 + w*16 + l4*4 + r;
    if(gr < NNODE){
      #pragma unroll
      for(int nf=0;nf<8;nf++)
        SRCw[(size_t)gr*HIDN + nf*16 + lm] = s2bf(acc[nf][r]);
      #pragma unroll
      for(int nf=8;nf<16;nf++)
        DSTw[(size_t)gr*HIDN + (nf-8)*16 + lm] = s2bf(acc[nf][r]);
    }
  }
}

// ---------------- union kernel: bi bins [0,NBIN) + flat d-sorted edge heads (after) ----------------
__global__ __launch_bounds__(256) void edgebi2_kernel(const u16t* __restrict__ SRCb,
                                                      const u16t* __restrict__ DSTb,
                                                      const float* __restrict__ nin,
                                                      const float* __restrict__ nout,
                                                      float* __restrict__ ein,
                                                      float* __restrict__ eout,
                                                      const u64t* __restrict__ bbuck,
                                                      const u32t* __restrict__ bcoff,
                                                      const u64t* __restrict__ ebuck,
                                                      const float* __restrict__ nn,
                                                      float* __restrict__ outp){
  __shared__ u64t ebuf[CAPB];
  __shared__ u32t hist[128], offs[129], cur[128], sc[128];
  const int t = threadIdx.x;
  const u32t* Sw = (const u32t*)SRCb;
  const u32t* Dw = (const u32t*)DSTb;
  const int w = t>>6, l = t&63;
  if(blockIdx.x >= NBIN){
    // ---------- edge path: flat grid over d-sorted ebuck, 8 edges/wave ----------
    const int i0 = ((int)(blockIdx.x - NBIN)*4 + w)*8;    // all 8 valid: EBLK*32 == EDIR
    u32t eq[8], sq[8], dq[8];
    #pragma unroll
    for(int q=0;q<8;q++){
      u64t en = ebuck[i0+q];
      sq[q] = (u32t)en & 0x1FFFFu;
      dq[q] = (u32t)(en>>17) & 0x1FFFFu;
      eq[q] = (u32t)(en>>34);
    }
    float2 Ss[8], Ds[8], Sd[8], Dd[8];
    float ni[8], no[8];
    #pragma unroll
    for(int q=0;q<8;q++){
      Ss[q] = up2(Sw[(size_t)sq[q]*64 + l]);
      Ds[q] = up2(Dw[(size_t)sq[q]*64 + l]);
      Sd[q] = up2(Sw[(size_t)dq[q]*64 + l]);
      Dd[q] = up2(Dw[(size_t)dq[q]*64 + l]);
      ni[q] = __builtin_nontemporal_load(&nin[(size_t)eq[q]*DOUTN + l]);
      no[q] = __builtin_nontemporal_load(&nout[(size_t)eq[q]*DOUTN + l]);
    }
    #pragma unroll
    for(int q=0;q<8;q++){
      size_t o = (size_t)eq[q]*DOUTN + l;
      float miu_in  = Ss[q].x + Dd[q].x, ls_in  = Ss[q].y + Dd[q].y;
      float miu_out = Sd[q].x + Ds[q].x, ls_out = Sd[q].y + Ds[q].y;
      __builtin_nontemporal_store(ni[q] * __expf(ls_in)  + miu_in,  &ein[o]);
      __builtin_nontemporal_store(no[q] * __expf(ls_out) + miu_out, &eout[o]);
    }
    return;
  }
  // ---------- bi path: bin-per-block in-LDS CSR + gather + finalize ----------
  int bin = blockIdx.x;
  u32t base = bcoff[bin], cnt = bcoff[bin+1] - base;
  if(t<128) hist[t]=0;
  __syncthreads();
  for(u32t i=t;i<cnt;i+=256)
    atomicAdd(&hist[(u32t)(bbuck[base+i]>>20)&127u], 1u);
  __syncthreads();
  if(t<128) sc[t]=hist[t];
  __syncthreads();
  for(int off=1;off<128;off<<=1){
    u32t x=(t>=off&&t<128)?sc[t-off]:0u;
    __syncthreads();
    if(t<128) sc[t]+=x;
    __syncthreads();
  }
  if(t<128){ offs[t+1]=sc[t]; cur[t]=sc[t]-hist[t]; if(t==0) offs[0]=0u; }
  __syncthreads();
  for(u32t i=t;i<cnt;i+=256){
    u64t e = bbuck[base+i];
    u32t p = atomicAdd(&cur[(u32t)(e>>20)&127u], 1u);
    ebuf[p]=e;
  }
  __syncthreads();
  for(int idx=w; idx<128; idx+=4){
    int n = bin*128 + idx;
    if(n >= NNODE) continue;
    float2 S = up2(Sw[(size_t)n*64 + l]);
    u32t s0=offs[idx], cnt2=offs[idx+1]-s0;
    float nmiu=0.f, nvar=0.f;
    u32t nbr=(cnt2+3)&~3u;
    for(u32t j=0;j<nbr;j+=4){
      float2 Dq[4]; float vs[4];
      #pragma unroll
      for(int q=0;q<4;q++){
        u32t jj=j+q;
        u64t e=(jj<cnt2)? ebuf[s0+jj] : 0ULL;
        vs[q]=__uint_as_float((u32t)(e>>32));
        Dq[q]=up2(Dw[(size_t)(e&0x1FFFFu)*64 + l]);
      }
      #pragma unroll
      for(int q=0;q<4;q++){
        nmiu += vs[q]*(S.x+Dq[q].x);
        nvar += vs[q]*vs[q]*__expf(S.y+Dq[q].y);
      }
    }
    size_t o = (size_t)n*DOUTN + l;
    float nd = __builtin_nontemporal_load(&nn[o]);
    __builtin_nontemporal_store(nd*sqrtf(nvar) + nmiu, &outp[o]);  // exp(0.5*log v)==sqrt(v)
  }
}

extern "C" void kernel_launch(void* const* d_in, const int* in_sizes, int n_in,
                              void* d_out, int out_size, void* d_ws, size_t ws_size,
                              hipStream_t stream){
  const float* X    = (const float*)d_in[0];
  const float* Wg   = (const float*)d_in[1];
  const float* Wm   = (const float*)d_in[2];
  const float* Wsg  = (const float*)d_in[3];
  const float* gv   = (const float*)d_in[4];
  const float* bv   = (const float*)d_in[5];
  const float* nin  = (const float*)d_in[6];
  const float* nout = (const float*)d_in[7];
  const float* nnod = (const float*)d_in[8];
  const int*  gi   = (const int*)d_in[9];
  const int*  ed   = (const int*)d_in[10];
  const int*  be   = (const int*)d_in[11];

  // workspace (76.8 MB):
  //  [0,12.8M)          gbuck u64 (dead after gather)   -> phase2: DSTw bf16 [0,25.6M)
  //  [12.8M,38.4M)      xwb bf16 (dead after gather)    -> (tail of DSTw)
  //  [38.40M,+36K)      meta: gcnt|bcnt|ecnt|gcoff|gcur|bcoff|bcur|ecoff|ecur (4KB each)
  //  [38.44M,46.44M)    bbuck u64 (live until edgebi2)
  //  [46.44M,50.44M)    ebuck u64 (live until edgebi2)
  //  [51.2M,76.8M)      hiddenw -> in-place SRCw bf16 after gemm2
  char* ws = (char*)d_ws;
  u64t*  gbuck   = (u64t*)ws;
  u16t*  xwb     = (u16t*)(ws + 12800000);
  u32t*  gcnt_c  = (u32t*)(ws + 38400000);
  u32t*  bcnt_c  = (u32t*)(ws + 38404096);
  u32t*  ecnt_c  = (u32t*)(ws + 38408192);
  u32t*  gcoff   = (u32t*)(ws + 38412288);
  u32t*  gcur_   = (u32t*)(ws + 38416384);
  u32t*  bcoff   = (u32t*)(ws + 38420480);
  u32t*  bcur_   = (u32t*)(ws + 38424576);
  u32t*  ecoff   = (u32t*)(ws + 38428672);
  u32t*  ecur_   = (u32t*)(ws + 38432768);
  u64t*  bbuck   = (u64t*)(ws + 38440000);
  u64t*  ebuck   = (u64t*)(ws + 46440000);
  u32t*  hiddenw = (u32t*)(ws + 51200000);
  u16t*  SRCw    = (u16t*)hiddenw;
  u16t*  DSTw    = (u16t*)ws;

  float* out  = (float*)d_out;
  float* ein  = out + (size_t)NNODE*DOUTN;
  float* eout = ein + (size_t)EDIR*DOUTN;
  // weight-prep arrays in tail of d_out's node region; dead before edgebi2 overwrites
  u16t* Wg_pre = (u16t*)((char*)d_out + 25600000 - 131072);
  u16t* Wc_pre = Wg_pre + 32768;

  (void)hipMemsetAsync(gcnt_c, 0, 12288, stream);               // gcnt + bcnt + ecnt
  histprep_kernel   <<<KPART+256, 256, 0, stream>>>(gi, be, ed, gcnt_c, bcnt_c, ecnt_c,
                                                    Wg, Wm, Wsg, Wg_pre, Wc_pre);
  scan_coarse_kernel<<<3,         256, 0, stream>>>(gcnt_c, gcoff, gcur_, bcnt_c, bcoff, bcur_,
                                                    ecnt_c, ecoff, ecur_);
  partgemm1_kernel  <<<G64+KPART, 256, 0, stream>>>(X, Wg_pre, xwb,
                                                    gi, gv, be, bv, ed,
                                                    gcur_, gbuck, bcur_, bbuck, ecur_, ebuck);
  gcn_gather2_kernel<<<NBIN,      256, 0, stream>>>(xwb, gbuck, gcoff, hiddenw);
  gemm2_kernel      <<<G64,       256, 0, stream>>>(hiddenw, Wc_pre, DSTw);
  edgebi2_kernel    <<<NBIN+EBLK, 256, 0, stream>>>(SRCw, DSTw, nin, nout,
                                                    ein, eout, bbuck, bcoff,
                                                    ebuck, nnod, out);
}

// Round 20
// 368.163 us; speedup vs baseline: 1.3078x; 1.0336x over previous
//
#include <hip/hip_runtime.h>
#include <hip/hip_bf16.h>

typedef unsigned short u16t;
typedef unsigned int   u32t;
typedef unsigned long long u64t;

#define NNODE 100000
#define DIN   256
#define HIDN  128
#define DOUTN 64
#define NNZE  1600000
#define EDIR  500000
#define EBI   1000000
#define G64   1563           // ceil(NNODE/64)
#define NBIN  782            // ceil(NNODE/128), bin = key>>7
#define CH3   4096           // edges per partition block
#define K3G   391            // ceil(NNZE/CH3)
#define K3B   245            // ceil(EBI/CH3)
#define K3E   123            // ceil(EDIR/CH3)
#define KPART (K3G+K3B+K3E)  // 759 partition blocks
#define CAPG  2432           // gcn entries per bin cap
#define CAPB  1536           // bi entries per bin cap
#define EBLK  15625          // EDIR/32: flat edge blocks (8 edges/wave, 4 waves)
#define NXCD  8

typedef __attribute__((ext_vector_type(8))) short bf16x8;
typedef __attribute__((ext_vector_type(4))) float f32x4;
typedef __attribute__((ext_vector_type(4))) float f4v;

__device__ __forceinline__ u32t pk2bf(float a, float b){
  __hip_bfloat162 h = __float22bfloat162_rn(make_float2(a, b));
  union { __hip_bfloat162 h2; u32t u; } c; c.h2 = h; return c.u;
}
__device__ __forceinline__ u16t s2bf(float a){
  __hip_bfloat16 h = __float2bfloat16(a);
  union { __hip_bfloat16 h1; u16t u; } c; c.h1 = h; return c.u;
}
__device__ __forceinline__ float2 up2(u32t w){
  return make_float2(__uint_as_float(w<<16), __uint_as_float(w&0xFFFF0000u));
}

// ---------------- union: coarse histogram (3 streams) + weight prep ----------------
__global__ __launch_bounds__(256) void histprep_kernel(const int* __restrict__ gi,
                                                       const int* __restrict__ be,
                                                       const int* __restrict__ ed,
                                                       u32t* __restrict__ gcnt_c,
                                                       u32t* __restrict__ bcnt_c,
                                                       u32t* __restrict__ ecnt_c,
                                                       const float* __restrict__ Wg,
                                                       const float* __restrict__ Wm,
                                                       const float* __restrict__ Wsg,
                                                       u16t* __restrict__ Wg_pre,
                                                       u16t* __restrict__ Wc_pre){
  __shared__ u32t h[1024];
  int blk = blockIdx.x, t = threadIdx.x;
  if(blk >= KPART){
    int idx = (blk-KPART)*256 + t;              // 0..65535
    int e = idx & 7, l = (idx>>3) & 63, f = (idx>>9) & 63, sel = idx>>15;
    int k_in = ((e>>2)<<4) + ((l>>4)<<2) + (e&3);
    if(sel == 0){
      int ks = f>>3, nf = f&7;
      int k = ks*32 + k_in, n = nf*16 + (l&15);
      Wg_pre[idx] = s2bf(Wg[(size_t)k*HIDN + n]);
    } else {
      int ks = f>>4, nf = f&15;
      int k = ks*32 + k_in, c = nf*16 + (l&15);
      int half = c>>7, ci = c&127;
      const float* src = (ci&1) ? Wsg : Wm;
      Wc_pre[idx - 32768] = s2bf(src[(size_t)(half*128 + k)*DOUTN + (ci>>1)]);
    }
    return;
  }
  const int* keys; u32t* outc; int E, e0;
  if(blk < K3G)          { keys=gi;      outc=gcnt_c; E=NNZE; e0=blk*CH3; }
  else if(blk < K3G+K3B) { keys=be;      outc=bcnt_c; E=EBI;  e0=(blk-K3G)*CH3; }
  else                   { keys=ed+EDIR; outc=ecnt_c; E=EDIR; e0=(blk-K3G-K3B)*CH3; }  // key = d
  for(int i=t;i<1024;i+=256) h[i]=0;
  __syncthreads();
  for(int i=t;i<CH3;i+=256){
    int e=e0+i;
    if(e<E) atomicAdd(&h[(u32t)keys[e]>>7], 1u);
  }
  __syncthreads();
  for(int b=t;b<1024;b+=256){
    u32t c=h[b];
    if(c) atomicAdd(&outc[b], c);
  }
}

// ---------------- scan coarse counts -> offsets + cursors (3 blocks) ----------------
__global__ __launch_bounds__(256) void scan_coarse_kernel(u32t* __restrict__ gcnt_c,
                                                          u32t* __restrict__ gcoff,
                                                          u32t* __restrict__ gcur_,
                                                          u32t* __restrict__ bcnt_c,
                                                          u32t* __restrict__ bcoff,
                                                          u32t* __restrict__ bcur_,
                                                          u32t* __restrict__ ecnt_c,
                                                          u32t* __restrict__ ecoff,
                                                          u32t* __restrict__ ecur_){
  __shared__ u32t part[256];
  u32t *cnt, *coff, *cur;
  if(blockIdx.x==0)      { cnt=gcnt_c; coff=gcoff; cur=gcur_; }
  else if(blockIdx.x==1) { cnt=bcnt_c; coff=bcoff; cur=bcur_; }
  else                   { cnt=ecnt_c; coff=ecoff; cur=ecur_; }
  int t = threadIdx.x;
  u32t ch[4], s=0;
  #pragma unroll
  for(int j=0;j<4;j++){ int idx=t*4+j; ch[j] = (idx<NBIN)? cnt[idx] : 0u; s+=ch[j]; }
  part[t]=s; __syncthreads();
  for(int off=1;off<256;off<<=1){
    u32t x=(t>=off)?part[t-off]:0u;
    __syncthreads();
    part[t]+=x;
    __syncthreads();
  }
  u32t run=(t==0)?0u:part[t-1];
  #pragma unroll
  for(int j=0;j<4;j++){
    int idx=t*4+j;
    if(idx<NBIN){ coff[idx]=run; cur[idx]=run; run+=ch[j]; }
  }
  if(t==255) coff[NBIN]=part[255];
}

// ---------------- union: GEMM1 (blocks [0,G64)) + partition (3 streams, after) ----------------
__global__ __launch_bounds__(256) void partgemm1_kernel(const float* __restrict__ X,
                                                        const u16t* __restrict__ Wg_pre,
                                                        u16t* __restrict__ xwb,
                                                        const int* __restrict__ gi,
                                                        const float* __restrict__ gv,
                                                        const int* __restrict__ be,
                                                        const float* __restrict__ bv,
                                                        const int* __restrict__ ed,
                                                        u32t* __restrict__ gcur_,
                                                        u64t* __restrict__ gbuck,
                                                        u32t* __restrict__ bcur_,
                                                        u64t* __restrict__ bbuck,
                                                        u32t* __restrict__ ecur_,
                                                        u64t* __restrict__ ebuck){
  __shared__ __align__(16) char smem[50176];
  const int t = threadIdx.x;
  if(blockIdx.x < G64){
    // ---------------- GEMM1 path ----------------
    u16t* Xs = (u16t*)smem;                     // 32 KB, 8B-granule XOR-swizzled
    const int l = t & 63, w = t >> 6;
    const int row0 = blockIdx.x * 64;
    for(int i=0;i<16;i++){
      int m = w*16 + i;
      int mg = min(row0 + m, NNODE-1);
      f4v f = __builtin_nontemporal_load((const f4v*)&X[(size_t)mg*DIN + l*4]);
      u32t* p = (u32t*)&Xs[m*256 + ((l ^ (m&15))<<2)];
      p[0] = pk2bf(f[0], f[1]);
      p[1] = pk2bf(f[2], f[3]);
    }
    __syncthreads();
    f32x4 acc[8];
    #pragma unroll
    for(int nf=0;nf<8;nf++) acc[nf] = (f32x4)(0.f);
    const int lm = l & 15, l4 = l >> 4;
    const int mrow = w*16 + lm;
    #pragma unroll 1
    for(int ks=0; ks<8; ks++){
      int kg = ks*8 + l4;
      union { uint2 u2[2]; bf16x8 v; } a;
      a.u2[0] = *(const uint2*)&Xs[mrow*256 + ((kg     ^ lm)<<2)];
      a.u2[1] = *(const uint2*)&Xs[mrow*256 + (((kg+4) ^ lm)<<2)];
      #pragma unroll
      for(int nf=0;nf<8;nf++){
        union { uint4 u4; bf16x8 v; } b;
        b.u4 = *(const uint4*)&Wg_pre[(size_t)((ks*8+nf)*64 + l)*8];
        acc[nf] = __builtin_amdgcn_mfma_f32_16x16x32_bf16(a.v, b.v, acc[nf], 0, 0, 0);
      }
    }
    #pragma unroll
    for(int r=0;r<4;r++){
      int gr = row0 + w*16 + l4*4 + r;
      if(gr < NNODE){
        #pragma unroll
        for(int nf=0;nf<8;nf++)
          xwb[(size_t)gr*HIDN + nf*16 + lm] = s2bf(acc[nf][r]);
      }
    }
    return;
  }
  // ---------------- partition path (3 streams) ----------------
  u32t* hist = (u32t*)smem;
  u32t* scn  = (u32t*)(smem+4096);
  u32t* prt  = (u32t*)(smem+8192);
  u64t* ebuf = (u64t*)(smem+9216);
  u16t* bins = (u16t*)(smem+41984);
  int blk = blockIdx.x - G64;
  const int *keys, *pay; const float* val; u32t* cursor; u64t* buck; int E, e0; bool eStream=false;
  if(blk < K3G)          { keys=gi;      pay=gi+NNZE; val=gv; cursor=gcur_; buck=gbuck; E=NNZE; e0=blk*CH3; }
  else if(blk < K3G+K3B) { keys=be;      pay=be+EBI;  val=bv; cursor=bcur_; buck=bbuck; E=EBI;  e0=(blk-K3G)*CH3; }
  else                   { keys=ed+EDIR; pay=ed;      val=0;  cursor=ecur_; buck=ebuck; E=EDIR; e0=(blk-K3G-K3B)*CH3; eStream=true; }
  for(int i=t;i<1024;i+=256) hist[i]=0;
  __syncthreads();
  for(int i=t;i<CH3;i+=256){
    int e=e0+i;
    if(e<E) atomicAdd(&hist[(u32t)keys[e]>>7], 1u);
  }
  __syncthreads();
  u32t ch[4], s=0;
  #pragma unroll
  for(int j=0;j<4;j++){ ch[j]=hist[t*4+j]; s+=ch[j]; }
  prt[t]=s; __syncthreads();
  for(int off=1;off<256;off<<=1){
    u32t x=(t>=off)?prt[t-off]:0u;
    __syncthreads();
    prt[t]+=x;
    __syncthreads();
  }
  u32t run=(t==0)?0u:prt[t-1];
  #pragma unroll
  for(int j=0;j<4;j++){ scn[t*4+j]=run; run+=ch[j]; }
  __syncthreads();
  for(int i=t;i<1024;i+=256) hist[i]=scn[i];   // hist becomes local cursor
  __syncthreads();
  for(int i=t;i<CH3;i+=256){
    int e=e0+i;
    if(e<E){
      int k = keys[e];
      u32t b = (u32t)k>>7;
      u32t p = atomicAdd(&hist[b],1u);
      u64t ent;
      if(eStream){
        // s (17b) | d (17b, bits 17..33) | e (19b, bits 34..52)
        ent = (u64t)(u32t)pay[e] | ((u64t)(u32t)k<<17) | ((u64t)(u32t)e<<34);
      } else {
        ent = (u64t)((u32t)pay[e] | (((u32t)k&127u)<<20)) | ((u64t)__float_as_uint(val[e])<<32);
      }
      ebuf[p]=ent; bins[p]=(u16t)b;
    }
  }
  __syncthreads();
  for(int b=t;b<1024;b+=256){
    u32t c = hist[b]-scn[b];
    u32t bs = c ? atomicAdd(&cursor[b], c) : 0u;
    hist[b] = bs;
  }
  __syncthreads();
  int totalValid = prt[255];
  for(int i=t;i<totalValid;i+=256){
    u32t b = bins[i];
    buck[ (size_t)hist[b] + (u32t)i - scn[b] ] = ebuf[i];
  }
}

// ---------------- GCN gather: bin-per-block, in-LDS CSR + gather (8x MLP) ----------------
__global__ __launch_bounds__(256) void gcn_gather2_kernel(const u16t* __restrict__ xwb,
                                                          const u64t* __restrict__ gbuck,
                                                          const u32t* __restrict__ gcoff,
                                                          u32t* __restrict__ hiddenw){
  __shared__ u64t ebuf[CAPG];
  __shared__ u32t hist[128], offs[129], cur[128], sc[128];
  int bin = blockIdx.x, t = threadIdx.x;
  u32t base = gcoff[bin], cnt = gcoff[bin+1] - base;
  if(t<128) hist[t]=0;
  __syncthreads();
  for(u32t i=t;i<cnt;i+=256)
    atomicAdd(&hist[(u32t)(gbuck[base+i]>>20)&127u], 1u);
  __syncthreads();
  if(t<128) sc[t]=hist[t];
  __syncthreads();
  for(int off=1;off<128;off<<=1){
    u32t x=(t>=off&&t<128)?sc[t-off]:0u;
    __syncthreads();
    if(t<128) sc[t]+=x;
    __syncthreads();
  }
  if(t<128){ offs[t+1]=sc[t]; cur[t]=sc[t]-hist[t]; if(t==0) offs[0]=0u; }
  __syncthreads();
  for(u32t i=t;i<cnt;i+=256){
    u64t e = gbuck[base+i];
    u32t p = atomicAdd(&cur[(u32t)(e>>20)&127u], 1u);
    ebuf[p]=e;
  }
  __syncthreads();
  int w=t>>6, l=t&63;
  const u32t* xww=(const u32t*)xwb;
  for(int idx=w; idx<128; idx+=4){
    int n = bin*128 + idx;
    if(n >= NNODE) continue;
    u32t s0=offs[idx], cnt2=offs[idx+1]-s0;
    float acc0=0.f, acc1=0.f;
    u32t nbr=(cnt2+7)&~7u;
    for(u32t j=0;j<nbr;j+=8){
      float2 xs[8]; float vs[8];
      #pragma unroll
      for(int q=0;q<8;q++){
        u32t jj=j+q;
        u64t e=(jj<cnt2)? ebuf[s0+jj] : 0ULL;
        vs[q]=__uint_as_float((u32t)(e>>32));
        xs[q]=up2(xww[(size_t)(e&0x1FFFFu)*64 + l]);
      }
      #pragma unroll
      for(int q=0;q<8;q++){ acc0+=vs[q]*xs[q].x; acc1+=vs[q]*xs[q].y; }
    }
    hiddenw[(size_t)n*64 + l] = pk2bf(acc0, acc1);
  }
}

// ---------------- GEMM2 (MFMA): SRCw (in-place over hiddenw) + DSTw ----------------
__global__ __launch_bounds__(256) void gemm2_kernel(u32t* __restrict__ hiddenw,
                                                    const u16t* __restrict__ Wc_pre,
                                                    u16t* __restrict__ DSTw){
  __shared__ __align__(16) u16t Hs[64*128];   // 16 KB
  const int t = threadIdx.x, l = t & 63, w = t >> 6;
  const int row0 = blockIdx.x * 64;
  for(int i=0;i<16;i++){
    int m = w*16 + i;
    int mg = min(row0 + m, NNODE-1);
    u32t v = hiddenw[(size_t)mg*64 + l];
    *(u32t*)&Hs[m*128 + (((l>>1) ^ (m&15))<<2) + ((l&1)<<1)] = v;
  }
  __syncthreads();
  f32x4 acc[16];
  #pragma unroll
  for(int nf=0;nf<16;nf++) acc[nf] = (f32x4)(0.f);
  const int lm = l & 15, l4 = l >> 4;
  const int mrow = w*16 + lm;
  #pragma unroll 1
  for(int ks=0; ks<4; ks++){
    int kg = ks*8 + l4;
    union { uint2 u2[2]; bf16x8 v; } a;
    a.u2[0] = *(const uint2*)&Hs[mrow*128 + ((kg     ^ lm)<<2)];
    a.u2[1] = *(const uint2*)&Hs[mrow*128 + (((kg+4) ^ lm)<<2)];
    #pragma unroll
    for(int nf=0;nf<16;nf++){
      union { uint4 u4; bf16x8 v; } b;
      b.u4 = *(const uint4*)&Wc_pre[(size_t)((ks*16+nf)*64 + l)*8];
      acc[nf] = __builtin_amdgcn_mfma_f32_16x16x32_bf16(a.v, b.v, acc[nf], 0, 0, 0);
    }
  }
  u16t* SRCw = (u16t*)hiddenw;   // in-place: this block's rows were staged above
  #pragma unroll
  for(int r=0;r<4;r++){
    int gr = row0 + w*16 + l4*4 + r;
    if(gr < NNODE){
      #pragma unroll
      for(int nf=0;nf<8;nf++)
        SRCw[(size_t)gr*HIDN + nf*16 + lm] = s2bf(acc[nf][r]);
      #pragma unroll
      for(int nf=8;nf<16;nf++)
        DSTw[(size_t)gr*HIDN + (nf-8)*16 + lm] = s2bf(acc[nf][r]);
    }
  }
}

// ---------------- union kernel: bi bins [0,NBIN) + flat d-sorted edge heads (XCD-swizzled) ----------------
__global__ __launch_bounds__(256) void edgebi2_kernel(const u16t* __restrict__ SRCb,
                                                      const u16t* __restrict__ DSTb,
                                                      const float* __restrict__ nin,
                                                      const float* __restrict__ nout,
                                                      float* __restrict__ ein,
                                                      float* __restrict__ eout,
                                                      const u64t* __restrict__ bbuck,
                                                      const u32t* __restrict__ bcoff,
                                                      const u64t* __restrict__ ebuck,
                                                      const float* __restrict__ nn,
                                                      float* __restrict__ outp){
  __shared__ u64t ebuf[CAPB];
  __shared__ u32t hist[128], offs[129], cur[128], sc[128];
  const int t = threadIdx.x;
  const u32t* Sw = (const u32t*)SRCb;
  const u32t* Dw = (const u32t*)DSTb;
  const int w = t>>6, l = t&63;
  if(blockIdx.x >= NBIN){
    // ---------- edge path: flat grid over d-sorted ebuck, bijective XCD chunk swizzle ----------
    int orig = (int)blockIdx.x - NBIN;                      // [0, EBLK)
    const int q = EBLK / NXCD, r = EBLK % NXCD;             // 1953, 1
    int xcd = orig % NXCD, idx = orig / NXCD;
    int ebid = (xcd < r ? xcd*(q+1) : r*(q+1) + (xcd-r)*q) + idx;
    const int i0 = (ebid*4 + w)*8;                          // all 8 valid: EBLK*32 == EDIR
    u32t eq[8], sq[8], dq[8];
    #pragma unroll
    for(int qq=0;qq<8;qq++){
      u64t en = ebuck[i0+qq];
      sq[qq] = (u32t)en & 0x1FFFFu;
      dq[qq] = (u32t)(en>>17) & 0x1FFFFu;
      eq[qq] = (u32t)(en>>34);
    }
    float2 Ss[8], Ds[8], Sd[8], Dd[8];
    float ni[8], no[8];
    #pragma unroll
    for(int qq=0;qq<8;qq++){
      Ss[qq] = up2(Sw[(size_t)sq[qq]*64 + l]);
      Ds[qq] = up2(Dw[(size_t)sq[qq]*64 + l]);
      Sd[qq] = up2(Sw[(size_t)dq[qq]*64 + l]);
      Dd[qq] = up2(Dw[(size_t)dq[qq]*64 + l]);
      ni[qq] = __builtin_nontemporal_load(&nin[(size_t)eq[qq]*DOUTN + l]);
      no[qq] = __builtin_nontemporal_load(&nout[(size_t)eq[qq]*DOUTN + l]);
    }
    #pragma unroll
    for(int qq=0;qq<8;qq++){
      size_t o = (size_t)eq[qq]*DOUTN + l;
      float miu_in  = Ss[qq].x + Dd[qq].x, ls_in  = Ss[qq].y + Dd[qq].y;
      float miu_out = Sd[qq].x + Ds[qq].x, ls_out = Sd[qq].y + Ds[qq].y;
      __builtin_nontemporal_store(ni[qq] * __expf(ls_in)  + miu_in,  &ein[o]);
      __builtin_nontemporal_store(no[qq] * __expf(ls_out) + miu_out, &eout[o]);
    }
    return;
  }
  // ---------- bi path: bin-per-block in-LDS CSR + gather + finalize ----------
  int bin = blockIdx.x;
  u32t base = bcoff[bin], cnt = bcoff[bin+1] - base;
  if(t<128) hist[t]=0;
  __syncthreads();
  for(u32t i=t;i<cnt;i+=256)
    atomicAdd(&hist[(u32t)(bbuck[base+i]>>20)&127u], 1u);
  __syncthreads();
  if(t<128) sc[t]=hist[t];
  __syncthreads();
  for(int off=1;off<128;off<<=1){
    u32t x=(t>=off&&t<128)?sc[t-off]:0u;
    __syncthreads();
    if(t<128) sc[t]+=x;
    __syncthreads();
  }
  if(t<128){ offs[t+1]=sc[t]; cur[t]=sc[t]-hist[t]; if(t==0) offs[0]=0u; }
  __syncthreads();
  for(u32t i=t;i<cnt;i+=256){
    u64t e = bbuck[base+i];
    u32t p = atomicAdd(&cur[(u32t)(e>>20)&127u], 1u);
    ebuf[p]=e;
  }
  __syncthreads();
  for(int idx=w; idx<128; idx+=4){
    int n = bin*128 + idx;
    if(n >= NNODE) continue;
    float2 S = up2(Sw[(size_t)n*64 + l]);
    u32t s0=offs[idx], cnt2=offs[idx+1]-s0;
    float nmiu=0.f, nvar=0.f;
    u32t nbr=(cnt2+3)&~3u;
    for(u32t j=0;j<nbr;j+=4){
      float2 Dq[4]; float vs[4];
      #pragma unroll
      for(int qq=0;qq<4;qq++){
        u32t jj=j+qq;
        u64t e=(jj<cnt2)? ebuf[s0+jj] : 0ULL;
        vs[qq]=__uint_as_float((u32t)(e>>32));
        Dq[qq]=up2(Dw[(size_t)(e&0x1FFFFu)*64 + l]);
      }
      #pragma unroll
      for(int qq=0;qq<4;qq++){
        nmiu += vs[qq]*(S.x+Dq[qq].x);
        nvar += vs[qq]*vs[qq]*__expf(S.y+Dq[qq].y);
      }
    }
    size_t o = (size_t)n*DOUTN + l;
    float nd = __builtin_nontemporal_load(&nn[o]);
    __builtin_nontemporal_store(nd*sqrtf(nvar) + nmiu, &outp[o]);  // exp(0.5*log v)==sqrt(v)
  }
}

extern "C" void kernel_launch(void* const* d_in, const int* in_sizes, int n_in,
                              void* d_out, int out_size, void* d_ws, size_t ws_size,
                              hipStream_t stream){
  const float* X    = (const float*)d_in[0];
  const float* Wg   = (const float*)d_in[1];
  const float* Wm   = (const float*)d_in[2];
  const float* Wsg  = (const float*)d_in[3];
  const float* gv   = (const float*)d_in[4];
  const float* bv   = (const float*)d_in[5];
  const float* nin  = (const float*)d_in[6];
  const float* nout = (const float*)d_in[7];
  const float* nnod = (const float*)d_in[8];
  const int*  gi   = (const int*)d_in[9];
  const int*  ed   = (const int*)d_in[10];
  const int*  be   = (const int*)d_in[11];

  // workspace (76.8 MB):
  //  [0,12.8M)          gbuck u64 (dead after gather)   -> phase2: DSTw bf16 [0,25.6M)
  //  [12.8M,38.4M)      xwb bf16 (dead after gather)    -> (tail of DSTw)
  //  [38.40M,+36K)      meta: gcnt|bcnt|ecnt|gcoff|gcur|bcoff|bcur|ecoff|ecur (4KB each)
  //  [38.44M,46.44M)    bbuck u64 (live until edgebi2)
  //  [46.44M,50.44M)    ebuck u64 (live until edgebi2)
  //  [51.2M,76.8M)      hiddenw -> in-place SRCw bf16 after gemm2
  char* ws = (char*)d_ws;
  u64t*  gbuck   = (u64t*)ws;
  u16t*  xwb     = (u16t*)(ws + 12800000);
  u32t*  gcnt_c  = (u32t*)(ws + 38400000);
  u32t*  bcnt_c  = (u32t*)(ws + 38404096);
  u32t*  ecnt_c  = (u32t*)(ws + 38408192);
  u32t*  gcoff   = (u32t*)(ws + 38412288);
  u32t*  gcur_   = (u32t*)(ws + 38416384);
  u32t*  bcoff   = (u32t*)(ws + 38420480);
  u32t*  bcur_   = (u32t*)(ws + 38424576);
  u32t*  ecoff   = (u32t*)(ws + 38428672);
  u32t*  ecur_   = (u32t*)(ws + 38432768);
  u64t*  bbuck   = (u64t*)(ws + 38440000);
  u64t*  ebuck   = (u64t*)(ws + 46440000);
  u32t*  hiddenw = (u32t*)(ws + 51200000);
  u16t*  SRCw    = (u16t*)hiddenw;
  u16t*  DSTw    = (u16t*)ws;

  float* out  = (float*)d_out;
  float* ein  = out + (size_t)NNODE*DOUTN;
  float* eout = ein + (size_t)EDIR*DOUTN;
  // weight-prep arrays in tail of d_out's node region; dead before edgebi2 overwrites
  u16t* Wg_pre = (u16t*)((char*)d_out + 25600000 - 131072);
  u16t* Wc_pre = Wg_pre + 32768;

  (void)hipMemsetAsync(gcnt_c, 0, 12288, stream);               // gcnt + bcnt + ecnt
  histprep_kernel   <<<KPART+256, 256, 0, stream>>>(gi, be, ed, gcnt_c, bcnt_c, ecnt_c,
                                                    Wg, Wm, Wsg, Wg_pre, Wc_pre);
  scan_coarse_kernel<<<3,         256, 0, stream>>>(gcnt_c, gcoff, gcur_, bcnt_c, bcoff, bcur_,
                                                    ecnt_c, ecoff, ecur_);
  partgemm1_kernel  <<<G64+KPART, 256, 0, stream>>>(X, Wg_pre, xwb,
                                                    gi, gv, be, bv, ed,
                                                    gcur_, gbuck, bcur_, bbuck, ecur_, ebuck);
  gcn_gather2_kernel<<<NBIN,      256, 0, stream>>>(xwb, gbuck, gcoff, hiddenw);
  gemm2_kernel      <<<G64,       256, 0, stream>>>(hiddenw, Wc_pre, DSTw);
  edgebi2_kernel    <<<NBIN+EBLK, 256, 0, stream>>>(SRCw, DSTw, nin, nout,
                                                    ein, eout, bbuck, bcoff,
                                                    ebuck, nnod, out);
}